// Round 8
// baseline (246.724 us; speedup 1.0000x reference)
//
#include <hip/hip_runtime.h>

// DCNv3 forward, FP32 I/O. N=8, H=W=64, C=256, G=16, GC=16, K=3, P=9. L=32768.
//
// Round-18:
//  - Full revert to round-12 dataflow (best measured: 199.1us). Gather is
//    the round-12 8ch/thread NHWC version (R13/R14/R16/R17 all regressed it;
//    local optimum, do not touch).
//  - k_prep merged into k_dwln dispatch (blocks 8192..8449 run prep work;
//    dwln reads dw_w directly, stride-9 L1-resident -> no dwT, no ordering
//    hazard). 5 -> 4 dispatches.
//  - out-GEMM split to BM=64 tiles (k_gemm_out, grid 512x2 = 1024 blocks =
//    4 blocks/CU vs 2): doubles latency-hiding co-residency for the short-K
//    barrier-drain regime. Same K order + MFMA shape -> bit-identical.
// Dispatches: k_dwp, k_gemm_ih, k_gather, k_gemm_out.
// Fallback: round-3 minimal path (33.5 MB) if ws too small.

#define LL 32768
#define CC 256

typedef __bf16 bf16;
typedef __bf16 bf16x4 __attribute__((ext_vector_type(4)));
typedef __bf16 bf16x8 __attribute__((ext_vector_type(8)));
typedef float f32x4v __attribute__((ext_vector_type(4)));
typedef float f32x2 __attribute__((ext_vector_type(2)));

__device__ __forceinline__ void gload16(const bf16* g, const bf16* lds_base) {
    __builtin_amdgcn_global_load_lds(
        (const __attribute__((address_space(1))) void*)g,
        (__attribute__((address_space(3))) void*)lds_base, 16, 0, 0);
}

// ------- merged: dwconv3x3 + LN + GELU (blocks 0..8191) | prep (8192+) ----
__global__ __launch_bounds__(256) void k_dwp(
    const float* __restrict__ x, const float* __restrict__ dw_w,
    const float* __restrict__ dw_b, const float* __restrict__ ln_g,
    const float* __restrict__ ln_b, bf16* __restrict__ x1h,
    bf16* __restrict__ xb,
    const float* __restrict__ in_w, const float* __restrict__ off_w,
    const float* __restrict__ mask_w, const float* __restrict__ out_w,
    const float* __restrict__ off_b, const float* __restrict__ mask_b,
    bf16* __restrict__ in_h, bf16* __restrict__ hw_h,
    bf16* __restrict__ out_h, float* __restrict__ hbias) {
    int t = threadIdx.x;
    int b = blockIdx.x;
    if (b >= 8192) {
        // ---------------- weight prep: cvt + pack + pad -------------------
        int idx = (b - 8192) * 256 + t;
        if (idx < 60416) {
            const float* s; bf16* hi; int i;
            if (idx < 16384)      { s = in_w;   hi = in_h;          i = idx; }
            else if (idx < 34816) { s = off_w;  hi = hw_h;          i = idx - 16384; }
            else if (idx < 44032) { s = mask_w; hi = hw_h + 73728;  i = idx - 34816; }
            else                  { s = out_w;  hi = out_h;         i = idx - 44032; }
            float4 v = *(const float4*)(s + (size_t)i * 4);
            bf16x4 hh;
            hh[0] = (bf16)v.x; hh[1] = (bf16)v.y; hh[2] = (bf16)v.z; hh[3] = (bf16)v.w;
            *(bf16x4*)(hi + (size_t)i * 4) = hh;
        } else if (idx < 60928) {
            int e = idx - 60416;   // 0..511
            hbias[e] = (e < 288) ? off_b[e] : (e < 432 ? mask_b[e - 288] : 0.f);
        } else {
            int e = idx - 60928;   // 0..5119 : zero-fill hw rows 432..511
            bf16x4 z = {(bf16)0.f, (bf16)0.f, (bf16)0.f, (bf16)0.f};
            *(bf16x4*)(hw_h + 110592 + (size_t)e * 4) = z;
        }
        return;
    }
    // ------------------- dwconv3x3 + LN + GELU (wave/pixel) ---------------
    int q = t >> 6, u = t & 63;
    int l = b * 4 + q;
    int w = l & 63, h = (l >> 6) & 63, n = l >> 12;
    int c0 = u * 4;

    float4 acc = *(const float4*)(dw_b + c0);
    float4 xc = {0.f, 0.f, 0.f, 0.f};
    const float* wr0 = dw_w + (size_t)c0 * 9;   // 4 rows of 9 weights
#pragma unroll
    for (int kh = 0; kh < 3; ++kh) {
        int hh = h + kh - 1;
        if (hh < 0 || hh >= 64) continue;
#pragma unroll
        for (int kw = 0; kw < 3; ++kw) {
            int ww = w + kw - 1;
            if (ww < 0 || ww >= 64) continue;
            float4 xv = *(const float4*)(x + (size_t)(((n * 64 + hh) * 64) + ww) * CC + c0);
            if (kh == 1 && kw == 1) xc = xv;
            int j = kh * 3 + kw;
            acc.x += xv.x * wr0[j];
            acc.y += xv.y * wr0[9 + j];
            acc.z += xv.z * wr0[18 + j];
            acc.w += xv.w * wr0[27 + j];
        }
    }
    bf16x4 xcb;
    xcb[0] = (bf16)xc.x; xcb[1] = (bf16)xc.y;
    xcb[2] = (bf16)xc.z; xcb[3] = (bf16)xc.w;
    *(bf16x4*)(xb + (size_t)l * CC + c0) = xcb;

    float s = acc.x + acc.y + acc.z + acc.w;
    float ss = acc.x * acc.x + acc.y * acc.y + acc.z * acc.z + acc.w * acc.w;
#pragma unroll
    for (int d = 1; d < 64; d <<= 1) {
        s += __shfl_xor(s, d);
        ss += __shfl_xor(ss, d);
    }
    float mean = s * (1.0f / 256.0f);
    float var = ss * (1.0f / 256.0f) - mean * mean;
    float rstd = rsqrtf(var + 1e-6f);
    float4 gv = *(const float4*)(ln_g + c0);
    float4 bv = *(const float4*)(ln_b + c0);
    float xn0 = (acc.x - mean) * rstd * gv.x + bv.x;
    float xn1 = (acc.y - mean) * rstd * gv.y + bv.y;
    float xn2 = (acc.z - mean) * rstd * gv.z + bv.z;
    float xn3 = (acc.w - mean) * rstd * gv.w + bv.w;
    bf16x4 oh;
    oh[0] = (bf16)(0.5f * xn0 * (1.0f + erff(xn0 * 0.70710678118654752f)));
    oh[1] = (bf16)(0.5f * xn1 * (1.0f + erff(xn1 * 0.70710678118654752f)));
    oh[2] = (bf16)(0.5f * xn2 * (1.0f + erff(xn2 * 0.70710678118654752f)));
    oh[3] = (bf16)(0.5f * xn3 * (1.0f + erff(xn3 * 0.70710678118654752f)));
    *(bf16x4*)(x1h + (size_t)l * CC + c0) = oh;
}

// ---- 128x128-tile single-product bf16 MFMA GEMM, double-buffered ---------
// C = A@W^T + bias, bf16 out. K=256, BK=32. smem: 2 x (A | W), 32 KB.
__device__ __forceinline__ void gemm_core(
    const bf16* __restrict__ A, const bf16* __restrict__ Wh,
    const float* __restrict__ bias, bf16* __restrict__ Cbf,
    int Nout, int mb, int nb) {
    int t = threadIdx.x, wave = t >> 6, lane = t & 63;
    int wm = wave & 1, wn = wave >> 1;
    int fm = lane & 15, fq = lane >> 4;

    __shared__ bf16 smem[16384];   // buf b: [b*8192, b*8192+4096)=A, +4096=W

    const bf16* gbase[4];
    int lofs[4];
#pragma unroll
    for (int j = 0; j < 4; ++j) {
        int seg = wave * 4 + j;
        int arr = seg >> 3;
        int row = (seg & 7) * 16 + (lane >> 2);
        int col = (lane & 3) * 8;
        gbase[j] = (arr == 0) ? (A + (size_t)(mb + row) * CC + col)
                              : (Wh + (size_t)(nb + row) * CC + col);
        lofs[j] = seg * 512;
    }

    f32x4v acc[4][4];
#pragma unroll
    for (int i = 0; i < 4; ++i)
#pragma unroll
        for (int j = 0; j < 4; ++j) acc[i][j] = (f32x4v){0.f, 0.f, 0.f, 0.f};

#pragma unroll
    for (int j = 0; j < 4; ++j) gload16(gbase[j], smem + lofs[j]);

    for (int kt = 0; kt < 8; ++kt) {
        const bf16* buf = smem + (kt & 1) * 8192;
        bf16* nxt = smem + ((kt & 1) ^ 1) * 8192;
        __syncthreads();
        if (kt < 7) {
#pragma unroll
            for (int j = 0; j < 4; ++j)
                gload16(gbase[j] + (kt + 1) * 32, nxt + lofs[j]);
        }
        bf16x8 af[4], bfh[4];
#pragma unroll
        for (int i = 0; i < 4; ++i)
            af[i] = *(const bf16x8*)&buf[(wm * 64 + i * 16 + fm) * 32 + fq * 8];
#pragma unroll
        for (int j = 0; j < 4; ++j)
            bfh[j] = *(const bf16x8*)&buf[4096 + (wn * 64 + j * 16 + fm) * 32 + fq * 8];
#pragma unroll
        for (int i = 0; i < 4; ++i)
#pragma unroll
            for (int j = 0; j < 4; ++j)
                acc[i][j] = __builtin_amdgcn_mfma_f32_16x16x32_bf16(
                    af[i], bfh[j], acc[i][j], 0, 0, 0);
    }

    // D mapping: m = 16*tile + fq*4 + reg, n = 16*tile + fm
#pragma unroll
    for (int j = 0; j < 4; ++j) {
        int n_g = nb + wn * 64 + j * 16 + fm;
        if (n_g >= Nout) continue;
        float bv = bias[n_g];
#pragma unroll
        for (int i = 0; i < 4; ++i) {
            int m_g = mb + wm * 64 + i * 16 + fq * 4;
#pragma unroll
            for (int rg = 0; rg < 4; ++rg)
                Cbf[(size_t)(m_g + rg) * Nout + n_g] = (bf16)(acc[i][j][rg] + bv);
        }
    }
}

// Merged in-proj + head GEMM: grid (256, 6). y<2 -> in-proj (N=256),
// y>=2 -> offset/mask head (N=432 padded 512). 6 blocks/CU co-resident.
__global__ __launch_bounds__(256) void k_gemm_ih(
    const bf16* __restrict__ xb, const bf16* __restrict__ x1h,
    const bf16* __restrict__ in_h, const bf16* __restrict__ hw_h,
    const float* __restrict__ in_b, const float* __restrict__ hbias,
    bf16* __restrict__ xpb, bf16* __restrict__ headb) {
    int mb = blockIdx.x * 128;
    int y = blockIdx.y;
    if (y < 2)
        gemm_core(xb, in_h, in_b, xpb, 256, mb, y * 128);
    else
        gemm_core(x1h, hw_h, hbias, headb, 432, mb, (y - 2) * 128);
}

// ---- out-proj GEMM, BM=64 tiles for 4 blocks/CU: C32 = A@W^T + bias ------
// grid (512, 2). smem: 2 x (A 64x32 | W 128x32) = 24 KB. Same K order +
// MFMA shape as gemm_core -> bit-identical accumulation.
__global__ __launch_bounds__(256) void k_gemm_out(
    const bf16* __restrict__ A, const bf16* __restrict__ Wh,
    const float* __restrict__ bias, float* __restrict__ C32) {
    int mb = blockIdx.x * 64, nb = blockIdx.y * 128;
    int t = threadIdx.x, wave = t >> 6, lane = t & 63;
    int wm = wave & 1, wn = wave >> 1;
    int fm = lane & 15, fq = lane >> 4;

    __shared__ bf16 smem[12288];   // buf b: [b*6144, +2048)=A, +2048..6144=W

    const bf16* gbase[3];
    int lofs[3];
#pragma unroll
    for (int j = 0; j < 3; ++j) {
        int seg = wave * 3 + j;           // 0..11: segs 0-3 = A, 4-11 = W
        int r16 = (seg < 4) ? seg : (seg - 4);
        int row = r16 * 16 + (lane >> 2);
        int col = (lane & 3) * 8;
        gbase[j] = (seg < 4) ? (A + (size_t)(mb + row) * CC + col)
                             : (Wh + (size_t)(nb + row) * CC + col);
        lofs[j] = seg * 512;
    }

    f32x4v acc[2][4];
#pragma unroll
    for (int i = 0; i < 2; ++i)
#pragma unroll
        for (int j = 0; j < 4; ++j) acc[i][j] = (f32x4v){0.f, 0.f, 0.f, 0.f};

#pragma unroll
    for (int j = 0; j < 3; ++j) gload16(gbase[j], smem + lofs[j]);

    for (int kt = 0; kt < 8; ++kt) {
        const bf16* buf = smem + (kt & 1) * 6144;
        bf16* nxt = smem + ((kt & 1) ^ 1) * 6144;
        __syncthreads();
        if (kt < 7) {
#pragma unroll
            for (int j = 0; j < 3; ++j)
                gload16(gbase[j] + (kt + 1) * 32, nxt + lofs[j]);
        }
        bf16x8 af[2], bfh[4];
#pragma unroll
        for (int i = 0; i < 2; ++i)
            af[i] = *(const bf16x8*)&buf[(wm * 32 + i * 16 + fm) * 32 + fq * 8];
#pragma unroll
        for (int j = 0; j < 4; ++j)
            bfh[j] = *(const bf16x8*)&buf[2048 + (wn * 64 + j * 16 + fm) * 32 + fq * 8];
#pragma unroll
        for (int i = 0; i < 2; ++i)
#pragma unroll
            for (int j = 0; j < 4; ++j)
                acc[i][j] = __builtin_amdgcn_mfma_f32_16x16x32_bf16(
                    af[i], bfh[j], acc[i][j], 0, 0, 0);
    }

#pragma unroll
    for (int j = 0; j < 4; ++j) {
        int n_g = nb + wn * 64 + j * 16 + fm;
        float bv = bias[n_g];
#pragma unroll
        for (int i = 0; i < 2; ++i) {
            int m_g = mb + wm * 32 + i * 16 + fq * 4;
#pragma unroll
            for (int rg = 0; rg < 4; ++rg)
                C32[(size_t)(m_g + rg) * 256 + n_g] = acc[i][j][rg] + bv;
        }
    }
}

// ------ softmax + bilinear gather (8 ch/thread) — round-12 exact ----------
__device__ __forceinline__ void mac8(f32x2 acc[4], bf16x8 v, float wt) {
    union { bf16x8 b; unsigned u[4]; } cu;
    cu.b = v;
    f32x2 wv = {wt, wt};
#pragma unroll
    for (int i = 0; i < 4; ++i) {
        f32x2 a;
        a.x = __uint_as_float(cu.u[i] << 16);          // bf16 lo -> f32 exact
        a.y = __uint_as_float(cu.u[i] & 0xffff0000u);  // bf16 hi -> f32 exact
        acc[i] += a * wv;                              // contracts to pk fma
    }
}

__global__ __launch_bounds__(256) void k_gather(
    const bf16* __restrict__ xp, const bf16* __restrict__ head,
    bf16* __restrict__ rows) {
    int t = threadIdx.x;
    int q = t >> 5, u = t & 31;
    int l = blockIdx.x * 8 + q;
    int w = l & 63, h = (l >> 6) & 63, n = l >> 12;

    __shared__ float CW[8][576];   // stage: [0,288)=offs [288,432)=mask
    __shared__ int BASE[8][144];   // weights phase: CW[e*4..]=cw4, BASE[e]=idx

    for (int j = u; j < 432; j += 32) CW[q][j] = (float)head[(size_t)l * 432 + j];
    __syncthreads();

    if (u < 16) {
        int g = u;
        float mx = -1e30f;
#pragma unroll
        for (int p = 0; p < 9; ++p) mx = fmaxf(mx, CW[q][288 + g * 9 + p]);
        float s = 0.f, e[9];
#pragma unroll
        for (int p = 0; p < 9; ++p) { e[p] = expf(CW[q][288 + g * 9 + p] - mx); s += e[p]; }
        float inv = 1.0f / s;
#pragma unroll
        for (int p = 0; p < 9; ++p) CW[q][288 + g * 9 + p] = e[p] * inv;
    }
    __syncthreads();

    // phase 3: 144 (g,p) pairs / 32 threads: e = u, u+32, u+64, u+96, (u<16: u+128)
    float4 cwr[5];
    int baser[5];
#pragma unroll
    for (int k = 0; k < 5; ++k) {
        if (k < 4 || u < 16) {
            int ei = u + 32 * k;
            int g = ei / 9, p = ei - g * 9;
            float ox = CW[q][g * 18 + p * 2 + 0];
            float oy = CW[q][g * 18 + p * 2 + 1];
            float m  = CW[q][288 + ei];
            float ax = (float)(w + (p / 3) - 1) + ox;
            float ay = (float)(h + (p % 3) - 1) + oy;
            float x0f = floorf(ax), y0f = floorf(ay);
            int x0 = (int)x0f, y0 = (int)y0f;
            float tx = ax - x0f, ty = ay - y0f;
            int xb, yb;
            float wxa, wxb, wya, wyb;
            if (x0 < 0)       { xb = 0;  wxa = (x0 == -1) ? tx : 0.f; wxb = 0.f; }
            else if (x0 > 62) { xb = 62; wxa = 0.f; wxb = (x0 == 63) ? (1.f - tx) : 0.f; }
            else              { xb = x0; wxa = 1.f - tx; wxb = tx; }
            if (y0 < 0)       { yb = 0;  wya = (y0 == -1) ? ty : 0.f; wyb = 0.f; }
            else if (y0 > 62) { yb = 62; wya = 0.f; wyb = (y0 == 63) ? (1.f - ty) : 0.f; }
            else              { yb = y0; wya = 1.f - ty; wyb = ty; }
            float4 cw;
            cw.x = m * wxa * wya; cw.y = m * wxb * wya;
            cw.z = m * wxa * wyb; cw.w = m * wxb * wyb;
            cwr[k] = cw;
            baser[k] = (n << 20) + (yb * 64 + xb) * 256;
        }
    }
    __syncthreads();   // all offs/mask reads done before overwriting CW
#pragma unroll
    for (int k = 0; k < 5; ++k) {
        if (k < 4 || u < 16) {
            int ei = u + 32 * k;
            *(float4*)&CW[q][ei * 4] = cwr[k];
            BASE[q][ei] = baser[k];
        }
    }
    __syncthreads();

    // phase 4: sampling
    int g = u >> 1;
    int c0 = g * 16 + (u & 1) * 8;
    const bf16* xpc = xp + c0;
    f32x2 acc[4];
    acc[0] = (f32x2){0.f, 0.f}; acc[1] = (f32x2){0.f, 0.f};
    acc[2] = (f32x2){0.f, 0.f}; acc[3] = (f32x2){0.f, 0.f};
#pragma unroll
    for (int p = 0; p < 9; ++p) {
        int ei = g * 9 + p;
        float4 cw = *(const float4*)&CW[q][ei * 4];
        int base = BASE[q][ei];
        const bf16* p0 = xpc + base;
        const bf16* p1 = p0 + 16384;          // +1 row (64*256)
        bf16x8 v00 = *(const bf16x8*)(p0);
        bf16x8 v01 = *(const bf16x8*)(p0 + 256);
        bf16x8 v10 = *(const bf16x8*)(p1);
        bf16x8 v11 = *(const bf16x8*)(p1 + 256);
        mac8(acc, v00, cw.x);
        mac8(acc, v01, cw.y);
        mac8(acc, v10, cw.z);
        mac8(acc, v11, cw.w);
    }
    bf16x8 oh;
    oh[0] = (bf16)acc[0].x; oh[1] = (bf16)acc[0].y;
    oh[2] = (bf16)acc[1].x; oh[3] = (bf16)acc[1].y;
    oh[4] = (bf16)acc[2].x; oh[5] = (bf16)acc[2].y;
    oh[6] = (bf16)acc[3].x; oh[7] = (bf16)acc[3].y;
    *(bf16x8*)(rows + (size_t)l * CC + c0) = oh;
}

// ======================= round-3 minimal fallback =========================
__device__ __forceinline__ float dot256f(const float* a, const float* wrow) {
    const float4* w4 = (const float4*)wrow;
    float s = 0.f;
#pragma unroll 16
    for (int i = 0; i < 64; ++i) {
        float4 u = w4[i];
        const float* ap = a + i * 4;
        s += ap[0] * u.x + ap[1] * u.y + ap[2] * u.z + ap[3] * u.w;
    }
    return s;
}

__global__ __launch_bounds__(256) void k_inproj_fb(
    const float* __restrict__ x, const float* __restrict__ in_w,
    const float* __restrict__ in_b, float* __restrict__ xp) {
    int l = blockIdx.x;
    int t = threadIdx.x;
    __shared__ float xa[256];
    xa[t] = x[l * CC + t];
    __syncthreads();
    xp[l * CC + t] = dot256f(xa, in_w + t * CC) + in_b[t];
}

__device__ __forceinline__ float fetch_px_fb(const float* base, int yy, int xx) {
    if (xx < 0 || xx >= 64 || yy < 0 || yy >= 64) return 0.f;
    return base[(yy * 64 + xx) * CC];
}

__global__ __launch_bounds__(256) void k_main_fb(
    const float* __restrict__ x, const float* __restrict__ xp,
    const float* __restrict__ dw_w, const float* __restrict__ dw_b,
    const float* __restrict__ ln_g, const float* __restrict__ ln_b,
    const float* __restrict__ off_w, const float* __restrict__ off_b,
    const float* __restrict__ mask_w, const float* __restrict__ mask_b,
    const float* __restrict__ out_w, const float* __restrict__ out_b,
    float* __restrict__ out) {
    int l = blockIdx.x;
    int t = threadIdx.x;
    int w = l & 63, h = (l >> 6) & 63, n = l >> 12;
    __shared__ float x1[256];
    __shared__ float red[256];
    __shared__ float offs[288];
    __shared__ float ms[144];
    __shared__ float row[256];

    float acc = dw_b[t];
#pragma unroll
    for (int kh = 0; kh < 3; ++kh) {
        int hh = h + kh - 1;
        if (hh < 0 || hh >= 64) continue;
#pragma unroll
        for (int kw = 0; kw < 3; ++kw) {
            int ww = w + kw - 1;
            if (ww < 0 || ww >= 64) continue;
            acc += x[(((n * 64 + hh) * 64) + ww) * CC + t] * dw_w[t * 9 + kh * 3 + kw];
        }
    }
    red[t] = acc;
    __syncthreads();
    for (int s = 128; s > 0; s >>= 1) {
        if (t < s) red[t] += red[t + s];
        __syncthreads();
    }
    float mean = red[0] * (1.0f / 256.0f);
    __syncthreads();
    float d = acc - mean;
    red[t] = d * d;
    __syncthreads();
    for (int s = 128; s > 0; s >>= 1) {
        if (t < s) red[t] += red[t + s];
        __syncthreads();
    }
    float var = red[0] * (1.0f / 256.0f);
    float xn = d * rsqrtf(var + 1e-6f) * ln_g[t] + ln_b[t];
    x1[t] = 0.5f * xn * (1.0f + erff(xn * 0.70710678118654752f));
    __syncthreads();

    offs[t] = dot256f(x1, off_w + t * CC) + off_b[t];
    if (t < 32) {
        int j = 256 + t;
        offs[j] = dot256f(x1, off_w + j * CC) + off_b[j];
    }
    if (t < 144) ms[t] = dot256f(x1, mask_w + t * CC) + mask_b[t];
    __syncthreads();

    if (t < 16) {
        int g = t;
        float mx = -1e30f;
#pragma unroll
        for (int p = 0; p < 9; ++p) mx = fmaxf(mx, ms[g * 9 + p]);
        float s = 0.f, e[9];
#pragma unroll
        for (int p = 0; p < 9; ++p) { e[p] = expf(ms[g * 9 + p] - mx); s += e[p]; }
        float inv = 1.0f / s;
#pragma unroll
        for (int p = 0; p < 9; ++p) ms[g * 9 + p] = e[p] * inv;
    }
    __syncthreads();

    int g = t >> 4;
    const float* base = xp + (size_t)n * 64 * 64 * CC + t;
    float acc2 = 0.f;
#pragma unroll
    for (int p = 0; p < 9; ++p) {
        float ox = offs[g * 18 + p * 2 + 0];
        float oy = offs[g * 18 + p * 2 + 1];
        float ax = (float)(w + (p / 3) - 1) + ox;
        float ay = (float)(h + (p % 3) - 1) + oy;
        float x0f = floorf(ax), y0f = floorf(ay);
        int x0 = (int)x0f, y0 = (int)y0f;
        float tx = ax - x0f, ty = ay - y0f;
        float v00 = fetch_px_fb(base, y0, x0);
        float v01 = fetch_px_fb(base, y0, x0 + 1);
        float v10 = fetch_px_fb(base, y0 + 1, x0);
        float v11 = fetch_px_fb(base, y0 + 1, x0 + 1);
        float bl = (v00 * (1.f - tx) + v01 * tx) * (1.f - ty) +
                   (v10 * (1.f - tx) + v11 * tx) * ty;
        acc2 += ms[g * 9 + p] * bl;
    }
    row[t] = acc2;
    __syncthreads();
    out[l * CC + t] = dot256f(row, out_w + t * CC) + out_b[t];
}

// ==========================================================================
extern "C" void kernel_launch(void* const* d_in, const int* in_sizes, int n_in,
                              void* d_out, int out_size, void* d_ws,
                              size_t ws_size, hipStream_t stream) {
    const float* x      = (const float*)d_in[0];
    const float* dw_w   = (const float*)d_in[1];
    const float* dw_b   = (const float*)d_in[2];
    const float* ln_g   = (const float*)d_in[3];
    const float* ln_b   = (const float*)d_in[4];
    const float* off_w  = (const float*)d_in[5];
    const float* off_b  = (const float*)d_in[6];
    const float* mask_w = (const float*)d_in[7];
    const float* mask_b = (const float*)d_in[8];
    const float* in_w   = (const float*)d_in[9];
    const float* in_b   = (const float*)d_in[10];
    const float* out_w  = (const float*)d_in[11];
    const float* out_b  = (const float*)d_in[12];
    float* out = (float*)d_out;

    const size_t szBF    = (size_t)LL * CC * 2;     // 16,777,216
    const size_t szHEADB = (size_t)LL * 432 * 2;    // 28,311,552
    const size_t szWB    = 1048576;                 // weight blob
    const size_t need    = 3 * szBF + szHEADB + szWB;  // ~80 MB

    dim3 blk(256);
    if (ws_size >= need) {
        char* p = (char*)d_ws;
        bf16* x1h = (bf16*)p; p += szBF;       // reused as rows after head GEMM
        bf16* xpb = (bf16*)p; p += szBF;
        bf16* xb  = (bf16*)p; p += szBF;
        bf16* headb = (bf16*)p; p += szHEADB;
        bf16* in_h  = (bf16*)p; p += 131072;
        bf16* hw_h  = (bf16*)p; p += 262144;   // 512 x 256 bf16 (rows 432+ zeroed)
        bf16* out_h = (bf16*)p; p += 131072;
        float* hbias = (float*)p;
        bf16* rows = x1h;

        k_dwp<<<dim3(8450), blk, 0, stream>>>(
            x, dw_w, dw_b, ln_g, ln_b, x1h, xb,
            in_w, off_w, mask_w, out_w, off_b, mask_b,
            in_h, hw_h, out_h, hbias);
        k_gemm_ih<<<dim3(256, 6), blk, 0, stream>>>(
            xb, x1h, in_h, hw_h, in_b, hbias, xpb, headb);
        k_gather<<<dim3(LL / 8), blk, 0, stream>>>(xpb, headb, rows);
        k_gemm_out<<<dim3(512, 2), blk, 0, stream>>>(rows, out_h, out_b, out);
    } else {
        float* xp = (float*)d_ws;   // 33.5 MB
        k_inproj_fb<<<dim3(LL), blk, 0, stream>>>(x, in_w, in_b, xp);
        k_main_fb<<<dim3(LL), blk, 0, stream>>>(x, xp, dw_w, dw_b, ln_g, ln_b,
                                                off_w, off_b, mask_w, mask_b,
                                                out_w, out_b, out);
    }
}

// Round 9
// 206.410 us; speedup vs baseline: 1.1953x; 1.1953x over previous
//
#include <hip/hip_runtime.h>

// DCNv3 forward, FP32 I/O. N=8, H=W=64, C=256, G=16, GC=16, K=3, P=9. L=32768.
//
// Round-19:
//  - Round-18 post-mortem: k_dwp's direct dw_w reads (36 scalar loads at
//    144B lane stride) were the 85us regression. dwT transposed-table
//    staging (k_prep) restored -> k_dwln weight reads are coalesced float4.
//  - Dataflow = round-12 exactly (k_prep, k_dwln, k_gemm_ih, k_gather),
//    plus the ONE change from R18 worth keeping: out-GEMM BM=64 split
//    (k_gemm_out, grid 512x2 = 4 blocks/CU vs 2) — R18 validated its
//    bit-exactness (absmax unchanged); this round measures its speed.
// Dispatches: k_prep, k_dwln, k_gemm_ih, k_gather, k_gemm_out.
// Fallback: round-3 minimal path (33.5 MB) if ws too small.

#define LL 32768
#define CC 256

typedef __bf16 bf16;
typedef __bf16 bf16x4 __attribute__((ext_vector_type(4)));
typedef __bf16 bf16x8 __attribute__((ext_vector_type(8)));
typedef float f32x4v __attribute__((ext_vector_type(4)));
typedef float f32x2 __attribute__((ext_vector_type(2)));

__device__ __forceinline__ void gload16(const bf16* g, const bf16* lds_base) {
    __builtin_amdgcn_global_load_lds(
        (const __attribute__((address_space(1))) void*)g,
        (__attribute__((address_space(3))) void*)lds_base, 16, 0, 0);
}

// ---------------- weight prep: cvt + pack + pad, one launch ---------------
__global__ __launch_bounds__(256) void k_prep(
    const float* __restrict__ in_w, const float* __restrict__ off_w,
    const float* __restrict__ mask_w, const float* __restrict__ out_w,
    const float* __restrict__ dw_w, const float* __restrict__ off_b,
    const float* __restrict__ mask_b,
    bf16* __restrict__ in_h, bf16* __restrict__ hw_h,
    bf16* __restrict__ out_h,
    float* __restrict__ dwT, float* __restrict__ hbias) {
    int idx = blockIdx.x * 256 + threadIdx.x;
    if (idx < 60416) {
        const float* s; bf16* hi; int i;
        if (idx < 16384)      { s = in_w;   hi = in_h;          i = idx; }
        else if (idx < 34816) { s = off_w;  hi = hw_h;          i = idx - 16384; }
        else if (idx < 44032) { s = mask_w; hi = hw_h + 73728;  i = idx - 34816; }
        else                  { s = out_w;  hi = out_h;         i = idx - 44032; }
        float4 v = *(const float4*)(s + (size_t)i * 4);
        bf16x4 h;
        h[0] = (bf16)v.x; h[1] = (bf16)v.y; h[2] = (bf16)v.z; h[3] = (bf16)v.w;
        *(bf16x4*)(hi + (size_t)i * 4) = h;
    } else if (idx < 62720) {
        int e = idx - 60416;
        int c = e & 255, j = e >> 8;
        dwT[j * 256 + c] = dw_w[c * 9 + j];
    } else if (idx < 63232) {
        int e = idx - 62720;   // 0..511
        hbias[e] = (e < 288) ? off_b[e] : (e < 432 ? mask_b[e - 288] : 0.f);
    } else if (idx < 68352) {
        int e = idx - 63232;   // 0..5119 : zero-fill hw rows 432..511
        bf16x4 z = {(bf16)0.f, (bf16)0.f, (bf16)0.f, (bf16)0.f};
        *(bf16x4*)(hw_h + 110592 + (size_t)e * 4) = z;
    }
}

// ------- dwconv3x3 + LN + GELU (wave/pixel); also emits xb = bf16(x) ------
__global__ __launch_bounds__(256) void k_dwln(
    const float* __restrict__ x, const float* __restrict__ dwT,
    const float* __restrict__ dw_b, const float* __restrict__ ln_g,
    const float* __restrict__ ln_b, bf16* __restrict__ x1h,
    bf16* __restrict__ xb) {
    int t = threadIdx.x;
    int q = t >> 6, u = t & 63;
    int l = blockIdx.x * 4 + q;
    int w = l & 63, h = (l >> 6) & 63, n = l >> 12;
    int c0 = u * 4;

    float4 acc = *(const float4*)(dw_b + c0);
    float4 xc = {0.f, 0.f, 0.f, 0.f};
#pragma unroll
    for (int kh = 0; kh < 3; ++kh) {
        int hh = h + kh - 1;
        if (hh < 0 || hh >= 64) continue;
#pragma unroll
        for (int kw = 0; kw < 3; ++kw) {
            int ww = w + kw - 1;
            if (ww < 0 || ww >= 64) continue;
            float4 xv = *(const float4*)(x + (size_t)(((n * 64 + hh) * 64) + ww) * CC + c0);
            if (kh == 1 && kw == 1) xc = xv;
            float4 wv = *(const float4*)(dwT + (kh * 3 + kw) * 256 + c0);
            acc.x += xv.x * wv.x; acc.y += xv.y * wv.y;
            acc.z += xv.z * wv.z; acc.w += xv.w * wv.w;
        }
    }
    bf16x4 xcb;
    xcb[0] = (bf16)xc.x; xcb[1] = (bf16)xc.y;
    xcb[2] = (bf16)xc.z; xcb[3] = (bf16)xc.w;
    *(bf16x4*)(xb + (size_t)l * CC + c0) = xcb;

    float s = acc.x + acc.y + acc.z + acc.w;
    float ss = acc.x * acc.x + acc.y * acc.y + acc.z * acc.z + acc.w * acc.w;
#pragma unroll
    for (int d = 1; d < 64; d <<= 1) {
        s += __shfl_xor(s, d);
        ss += __shfl_xor(ss, d);
    }
    float mean = s * (1.0f / 256.0f);
    float var = ss * (1.0f / 256.0f) - mean * mean;
    float rstd = rsqrtf(var + 1e-6f);
    float4 gv = *(const float4*)(ln_g + c0);
    float4 bv = *(const float4*)(ln_b + c0);
    float xn0 = (acc.x - mean) * rstd * gv.x + bv.x;
    float xn1 = (acc.y - mean) * rstd * gv.y + bv.y;
    float xn2 = (acc.z - mean) * rstd * gv.z + bv.z;
    float xn3 = (acc.w - mean) * rstd * gv.w + bv.w;
    bf16x4 oh;
    oh[0] = (bf16)(0.5f * xn0 * (1.0f + erff(xn0 * 0.70710678118654752f)));
    oh[1] = (bf16)(0.5f * xn1 * (1.0f + erff(xn1 * 0.70710678118654752f)));
    oh[2] = (bf16)(0.5f * xn2 * (1.0f + erff(xn2 * 0.70710678118654752f)));
    oh[3] = (bf16)(0.5f * xn3 * (1.0f + erff(xn3 * 0.70710678118654752f)));
    *(bf16x4*)(x1h + (size_t)l * CC + c0) = oh;
}

// ---- 128x128-tile single-product bf16 MFMA GEMM, double-buffered ---------
// C = A@W^T + bias, bf16 out. K=256, BK=32. smem: 2 x (A | W), 32 KB.
__device__ __forceinline__ void gemm_core(
    const bf16* __restrict__ A, const bf16* __restrict__ Wh,
    const float* __restrict__ bias, bf16* __restrict__ Cbf,
    int Nout, int mb, int nb) {
    int t = threadIdx.x, wave = t >> 6, lane = t & 63;
    int wm = wave & 1, wn = wave >> 1;
    int fm = lane & 15, fq = lane >> 4;

    __shared__ bf16 smem[16384];   // buf b: [b*8192, b*8192+4096)=A, +4096=W

    const bf16* gbase[4];
    int lofs[4];
#pragma unroll
    for (int j = 0; j < 4; ++j) {
        int seg = wave * 4 + j;
        int arr = seg >> 3;
        int row = (seg & 7) * 16 + (lane >> 2);
        int col = (lane & 3) * 8;
        gbase[j] = (arr == 0) ? (A + (size_t)(mb + row) * CC + col)
                              : (Wh + (size_t)(nb + row) * CC + col);
        lofs[j] = seg * 512;
    }

    f32x4v acc[4][4];
#pragma unroll
    for (int i = 0; i < 4; ++i)
#pragma unroll
        for (int j = 0; j < 4; ++j) acc[i][j] = (f32x4v){0.f, 0.f, 0.f, 0.f};

#pragma unroll
    for (int j = 0; j < 4; ++j) gload16(gbase[j], smem + lofs[j]);

    for (int kt = 0; kt < 8; ++kt) {
        const bf16* buf = smem + (kt & 1) * 8192;
        bf16* nxt = smem + ((kt & 1) ^ 1) * 8192;
        __syncthreads();
        if (kt < 7) {
#pragma unroll
            for (int j = 0; j < 4; ++j)
                gload16(gbase[j] + (kt + 1) * 32, nxt + lofs[j]);
        }
        bf16x8 af[4], bfh[4];
#pragma unroll
        for (int i = 0; i < 4; ++i)
            af[i] = *(const bf16x8*)&buf[(wm * 64 + i * 16 + fm) * 32 + fq * 8];
#pragma unroll
        for (int j = 0; j < 4; ++j)
            bfh[j] = *(const bf16x8*)&buf[4096 + (wn * 64 + j * 16 + fm) * 32 + fq * 8];
#pragma unroll
        for (int i = 0; i < 4; ++i)
#pragma unroll
            for (int j = 0; j < 4; ++j)
                acc[i][j] = __builtin_amdgcn_mfma_f32_16x16x32_bf16(
                    af[i], bfh[j], acc[i][j], 0, 0, 0);
    }

    // D mapping: m = 16*tile + fq*4 + reg, n = 16*tile + fm
#pragma unroll
    for (int j = 0; j < 4; ++j) {
        int n_g = nb + wn * 64 + j * 16 + fm;
        if (n_g >= Nout) continue;
        float bv = bias[n_g];
#pragma unroll
        for (int i = 0; i < 4; ++i) {
            int m_g = mb + wm * 64 + i * 16 + fq * 4;
#pragma unroll
            for (int rg = 0; rg < 4; ++rg)
                Cbf[(size_t)(m_g + rg) * Nout + n_g] = (bf16)(acc[i][j][rg] + bv);
        }
    }
}

// Merged in-proj + head GEMM: grid (256, 6). y<2 -> in-proj (N=256),
// y>=2 -> offset/mask head (N=432 padded 512). 6 blocks/CU co-resident.
__global__ __launch_bounds__(256) void k_gemm_ih(
    const bf16* __restrict__ xb, const bf16* __restrict__ x1h,
    const bf16* __restrict__ in_h, const bf16* __restrict__ hw_h,
    const float* __restrict__ in_b, const float* __restrict__ hbias,
    bf16* __restrict__ xpb, bf16* __restrict__ headb) {
    int mb = blockIdx.x * 128;
    int y = blockIdx.y;
    if (y < 2)
        gemm_core(xb, in_h, in_b, xpb, 256, mb, y * 128);
    else
        gemm_core(x1h, hw_h, hbias, headb, 432, mb, (y - 2) * 128);
}

// ---- out-proj GEMM, BM=64 tiles for 4 blocks/CU: C32 = A@W^T + bias ------
// grid (512, 2). smem: 2 x (A 64x32 | W 128x32) = 24 KB. Same K order +
// MFMA shape as gemm_core -> bit-identical accumulation (validated R18).
__global__ __launch_bounds__(256) void k_gemm_out(
    const bf16* __restrict__ A, const bf16* __restrict__ Wh,
    const float* __restrict__ bias, float* __restrict__ C32) {
    int mb = blockIdx.x * 64, nb = blockIdx.y * 128;
    int t = threadIdx.x, wave = t >> 6, lane = t & 63;
    int wm = wave & 1, wn = wave >> 1;
    int fm = lane & 15, fq = lane >> 4;

    __shared__ bf16 smem[12288];   // buf b: [b*6144, +2048)=A, +2048..6144=W

    const bf16* gbase[3];
    int lofs[3];
#pragma unroll
    for (int j = 0; j < 3; ++j) {
        int seg = wave * 3 + j;           // 0..11: segs 0-3 = A, 4-11 = W
        int r16 = (seg < 4) ? seg : (seg - 4);
        int row = r16 * 16 + (lane >> 2);
        int col = (lane & 3) * 8;
        gbase[j] = (seg < 4) ? (A + (size_t)(mb + row) * CC + col)
                             : (Wh + (size_t)(nb + row) * CC + col);
        lofs[j] = seg * 512;
    }

    f32x4v acc[2][4];
#pragma unroll
    for (int i = 0; i < 2; ++i)
#pragma unroll
        for (int j = 0; j < 4; ++j) acc[i][j] = (f32x4v){0.f, 0.f, 0.f, 0.f};

#pragma unroll
    for (int j = 0; j < 3; ++j) gload16(gbase[j], smem + lofs[j]);

    for (int kt = 0; kt < 8; ++kt) {
        const bf16* buf = smem + (kt & 1) * 6144;
        bf16* nxt = smem + ((kt & 1) ^ 1) * 6144;
        __syncthreads();
        if (kt < 7) {
#pragma unroll
            for (int j = 0; j < 3; ++j)
                gload16(gbase[j] + (kt + 1) * 32, nxt + lofs[j]);
        }
        bf16x8 af[2], bfh[4];
#pragma unroll
        for (int i = 0; i < 2; ++i)
            af[i] = *(const bf16x8*)&buf[(wm * 32 + i * 16 + fm) * 32 + fq * 8];
#pragma unroll
        for (int j = 0; j < 4; ++j)
            bfh[j] = *(const bf16x8*)&buf[2048 + (wn * 64 + j * 16 + fm) * 32 + fq * 8];
#pragma unroll
        for (int i = 0; i < 2; ++i)
#pragma unroll
            for (int j = 0; j < 4; ++j)
                acc[i][j] = __builtin_amdgcn_mfma_f32_16x16x32_bf16(
                    af[i], bfh[j], acc[i][j], 0, 0, 0);
    }

#pragma unroll
    for (int j = 0; j < 4; ++j) {
        int n_g = nb + wn * 64 + j * 16 + fm;
        float bv = bias[n_g];
#pragma unroll
        for (int i = 0; i < 2; ++i) {
            int m_g = mb + wm * 32 + i * 16 + fq * 4;
#pragma unroll
            for (int rg = 0; rg < 4; ++rg)
                C32[(size_t)(m_g + rg) * 256 + n_g] = acc[i][j][rg] + bv;
        }
    }
}

// ------ softmax + bilinear gather (8 ch/thread) — round-12 exact ----------
__device__ __forceinline__ void mac8(f32x2 acc[4], bf16x8 v, float wt) {
    union { bf16x8 b; unsigned u[4]; } cu;
    cu.b = v;
    f32x2 wv = {wt, wt};
#pragma unroll
    for (int i = 0; i < 4; ++i) {
        f32x2 a;
        a.x = __uint_as_float(cu.u[i] << 16);          // bf16 lo -> f32 exact
        a.y = __uint_as_float(cu.u[i] & 0xffff0000u);  // bf16 hi -> f32 exact
        acc[i] += a * wv;                              // contracts to pk fma
    }
}

__global__ __launch_bounds__(256) void k_gather(
    const bf16* __restrict__ xp, const bf16* __restrict__ head,
    bf16* __restrict__ rows) {
    int t = threadIdx.x;
    int q = t >> 5, u = t & 31;
    int l = blockIdx.x * 8 + q;
    int w = l & 63, h = (l >> 6) & 63, n = l >> 12;

    __shared__ float CW[8][576];   // stage: [0,288)=offs [288,432)=mask
    __shared__ int BASE[8][144];   // weights phase: CW[e*4..]=cw4, BASE[e]=idx

    for (int j = u; j < 432; j += 32) CW[q][j] = (float)head[(size_t)l * 432 + j];
    __syncthreads();

    if (u < 16) {
        int g = u;
        float mx = -1e30f;
#pragma unroll
        for (int p = 0; p < 9; ++p) mx = fmaxf(mx, CW[q][288 + g * 9 + p]);
        float s = 0.f, e[9];
#pragma unroll
        for (int p = 0; p < 9; ++p) { e[p] = expf(CW[q][288 + g * 9 + p] - mx); s += e[p]; }
        float inv = 1.0f / s;
#pragma unroll
        for (int p = 0; p < 9; ++p) CW[q][288 + g * 9 + p] = e[p] * inv;
    }
    __syncthreads();

    // phase 3: 144 (g,p) pairs / 32 threads: e = u, u+32, u+64, u+96, (u<16: u+128)
    float4 cwr[5];
    int baser[5];
#pragma unroll
    for (int k = 0; k < 5; ++k) {
        if (k < 4 || u < 16) {
            int ei = u + 32 * k;
            int g = ei / 9, p = ei - g * 9;
            float ox = CW[q][g * 18 + p * 2 + 0];
            float oy = CW[q][g * 18 + p * 2 + 1];
            float m  = CW[q][288 + ei];
            float ax = (float)(w + (p / 3) - 1) + ox;
            float ay = (float)(h + (p % 3) - 1) + oy;
            float x0f = floorf(ax), y0f = floorf(ay);
            int x0 = (int)x0f, y0 = (int)y0f;
            float tx = ax - x0f, ty = ay - y0f;
            int xb, yb;
            float wxa, wxb, wya, wyb;
            if (x0 < 0)       { xb = 0;  wxa = (x0 == -1) ? tx : 0.f; wxb = 0.f; }
            else if (x0 > 62) { xb = 62; wxa = 0.f; wxb = (x0 == 63) ? (1.f - tx) : 0.f; }
            else              { xb = x0; wxa = 1.f - tx; wxb = tx; }
            if (y0 < 0)       { yb = 0;  wya = (y0 == -1) ? ty : 0.f; wyb = 0.f; }
            else if (y0 > 62) { yb = 62; wya = 0.f; wyb = (y0 == 63) ? (1.f - ty) : 0.f; }
            else              { yb = y0; wya = 1.f - ty; wyb = ty; }
            float4 cw;
            cw.x = m * wxa * wya; cw.y = m * wxb * wya;
            cw.z = m * wxa * wyb; cw.w = m * wxb * wyb;
            cwr[k] = cw;
            baser[k] = (n << 20) + (yb * 64 + xb) * 256;
        }
    }
    __syncthreads();   // all offs/mask reads done before overwriting CW
#pragma unroll
    for (int k = 0; k < 5; ++k) {
        if (k < 4 || u < 16) {
            int ei = u + 32 * k;
            *(float4*)&CW[q][ei * 4] = cwr[k];
            BASE[q][ei] = baser[k];
        }
    }
    __syncthreads();

    // phase 4: sampling
    int g = u >> 1;
    int c0 = g * 16 + (u & 1) * 8;
    const bf16* xpc = xp + c0;
    f32x2 acc[4];
    acc[0] = (f32x2){0.f, 0.f}; acc[1] = (f32x2){0.f, 0.f};
    acc[2] = (f32x2){0.f, 0.f}; acc[3] = (f32x2){0.f, 0.f};
#pragma unroll
    for (int p = 0; p < 9; ++p) {
        int ei = g * 9 + p;
        float4 cw = *(const float4*)&CW[q][ei * 4];
        int base = BASE[q][ei];
        const bf16* p0 = xpc + base;
        const bf16* p1 = p0 + 16384;          // +1 row (64*256)
        bf16x8 v00 = *(const bf16x8*)(p0);
        bf16x8 v01 = *(const bf16x8*)(p0 + 256);
        bf16x8 v10 = *(const bf16x8*)(p1);
        bf16x8 v11 = *(const bf16x8*)(p1 + 256);
        mac8(acc, v00, cw.x);
        mac8(acc, v01, cw.y);
        mac8(acc, v10, cw.z);
        mac8(acc, v11, cw.w);
    }
    bf16x8 oh;
    oh[0] = (bf16)acc[0].x; oh[1] = (bf16)acc[0].y;
    oh[2] = (bf16)acc[1].x; oh[3] = (bf16)acc[1].y;
    oh[4] = (bf16)acc[2].x; oh[5] = (bf16)acc[2].y;
    oh[6] = (bf16)acc[3].x; oh[7] = (bf16)acc[3].y;
    *(bf16x8*)(rows + (size_t)l * CC + c0) = oh;
}

// ======================= round-3 minimal fallback =========================
__device__ __forceinline__ float dot256f(const float* a, const float* wrow) {
    const float4* w4 = (const float4*)wrow;
    float s = 0.f;
#pragma unroll 16
    for (int i = 0; i < 64; ++i) {
        float4 u = w4[i];
        const float* ap = a + i * 4;
        s += ap[0] * u.x + ap[1] * u.y + ap[2] * u.z + ap[3] * u.w;
    }
    return s;
}

__global__ __launch_bounds__(256) void k_inproj_fb(
    const float* __restrict__ x, const float* __restrict__ in_w,
    const float* __restrict__ in_b, float* __restrict__ xp) {
    int l = blockIdx.x;
    int t = threadIdx.x;
    __shared__ float xa[256];
    xa[t] = x[l * CC + t];
    __syncthreads();
    xp[l * CC + t] = dot256f(xa, in_w + t * CC) + in_b[t];
}

__device__ __forceinline__ float fetch_px_fb(const float* base, int yy, int xx) {
    if (xx < 0 || xx >= 64 || yy < 0 || yy >= 64) return 0.f;
    return base[(yy * 64 + xx) * CC];
}

__global__ __launch_bounds__(256) void k_main_fb(
    const float* __restrict__ x, const float* __restrict__ xp,
    const float* __restrict__ dw_w, const float* __restrict__ dw_b,
    const float* __restrict__ ln_g, const float* __restrict__ ln_b,
    const float* __restrict__ off_w, const float* __restrict__ off_b,
    const float* __restrict__ mask_w, const float* __restrict__ mask_b,
    const float* __restrict__ out_w, const float* __restrict__ out_b,
    float* __restrict__ out) {
    int l = blockIdx.x;
    int t = threadIdx.x;
    int w = l & 63, h = (l >> 6) & 63, n = l >> 12;
    __shared__ float x1[256];
    __shared__ float red[256];
    __shared__ float offs[288];
    __shared__ float ms[144];
    __shared__ float row[256];

    float acc = dw_b[t];
#pragma unroll
    for (int kh = 0; kh < 3; ++kh) {
        int hh = h + kh - 1;
        if (hh < 0 || hh >= 64) continue;
#pragma unroll
        for (int kw = 0; kw < 3; ++kw) {
            int ww = w + kw - 1;
            if (ww < 0 || ww >= 64) continue;
            acc += x[(((n * 64 + hh) * 64) + ww) * CC + t] * dw_w[t * 9 + kh * 3 + kw];
        }
    }
    red[t] = acc;
    __syncthreads();
    for (int s = 128; s > 0; s >>= 1) {
        if (t < s) red[t] += red[t + s];
        __syncthreads();
    }
    float mean = red[0] * (1.0f / 256.0f);
    __syncthreads();
    float d = acc - mean;
    red[t] = d * d;
    __syncthreads();
    for (int s = 128; s > 0; s >>= 1) {
        if (t < s) red[t] += red[t + s];
        __syncthreads();
    }
    float var = red[0] * (1.0f / 256.0f);
    float xn = d * rsqrtf(var + 1e-6f) * ln_g[t] + ln_b[t];
    x1[t] = 0.5f * xn * (1.0f + erff(xn * 0.70710678118654752f));
    __syncthreads();

    offs[t] = dot256f(x1, off_w + t * CC) + off_b[t];
    if (t < 32) {
        int j = 256 + t;
        offs[j] = dot256f(x1, off_w + j * CC) + off_b[j];
    }
    if (t < 144) ms[t] = dot256f(x1, mask_w + t * CC) + mask_b[t];
    __syncthreads();

    if (t < 16) {
        int g = t;
        float mx = -1e30f;
#pragma unroll
        for (int p = 0; p < 9; ++p) mx = fmaxf(mx, ms[g * 9 + p]);
        float s = 0.f, e[9];
#pragma unroll
        for (int p = 0; p < 9; ++p) { e[p] = expf(ms[g * 9 + p] - mx); s += e[p]; }
        float inv = 1.0f / s;
#pragma unroll
        for (int p = 0; p < 9; ++p) ms[g * 9 + p] = e[p] * inv;
    }
    __syncthreads();

    int g = t >> 4;
    const float* base = xp + (size_t)n * 64 * 64 * CC + t;
    float acc2 = 0.f;
#pragma unroll
    for (int p = 0; p < 9; ++p) {
        float ox = offs[g * 18 + p * 2 + 0];
        float oy = offs[g * 18 + p * 2 + 1];
        float ax = (float)(w + (p / 3) - 1) + ox;
        float ay = (float)(h + (p % 3) - 1) + oy;
        float x0f = floorf(ax), y0f = floorf(ay);
        int x0 = (int)x0f, y0 = (int)y0f;
        float tx = ax - x0f, ty = ay - y0f;
        float v00 = fetch_px_fb(base, y0, x0);
        float v01 = fetch_px_fb(base, y0, x0 + 1);
        float v10 = fetch_px_fb(base, y0 + 1, x0);
        float v11 = fetch_px_fb(base, y0 + 1, x0 + 1);
        float bl = (v00 * (1.f - tx) + v01 * tx) * (1.f - ty) +
                   (v10 * (1.f - tx) + v11 * tx) * ty;
        acc2 += ms[g * 9 + p] * bl;
    }
    row[t] = acc2;
    __syncthreads();
    out[l * CC + t] = dot256f(row, out_w + t * CC) + out_b[t];
}

// ==========================================================================
extern "C" void kernel_launch(void* const* d_in, const int* in_sizes, int n_in,
                              void* d_out, int out_size, void* d_ws,
                              size_t ws_size, hipStream_t stream) {
    const float* x      = (const float*)d_in[0];
    const float* dw_w   = (const float*)d_in[1];
    const float* dw_b   = (const float*)d_in[2];
    const float* ln_g   = (const float*)d_in[3];
    const float* ln_b   = (const float*)d_in[4];
    const float* off_w  = (const float*)d_in[5];
    const float* off_b  = (const float*)d_in[6];
    const float* mask_w = (const float*)d_in[7];
    const float* mask_b = (const float*)d_in[8];
    const float* in_w   = (const float*)d_in[9];
    const float* in_b   = (const float*)d_in[10];
    const float* out_w  = (const float*)d_in[11];
    const float* out_b  = (const float*)d_in[12];
    float* out = (float*)d_out;

    const size_t szBF    = (size_t)LL * CC * 2;     // 16,777,216
    const size_t szHEADB = (size_t)LL * 432 * 2;    // 28,311,552
    const size_t szWB    = 1048576;                 // weight blob
    const size_t need    = 3 * szBF + szHEADB + szWB;  // ~80 MB

    dim3 blk(256);
    if (ws_size >= need) {
        char* p = (char*)d_ws;
        bf16* x1h = (bf16*)p; p += szBF;       // reused as rows after head GEMM
        bf16* xpb = (bf16*)p; p += szBF;
        bf16* xb  = (bf16*)p; p += szBF;
        bf16* headb = (bf16*)p; p += szHEADB;
        bf16* in_h  = (bf16*)p; p += 131072;
        bf16* hw_h  = (bf16*)p; p += 262144;   // 512 x 256 bf16 (rows 432+ zeroed)
        bf16* out_h = (bf16*)p; p += 131072;
        float* dwT  = (float*)p; p += 9216;
        float* hbias = (float*)p;
        bf16* rows = x1h;

        k_prep<<<dim3(267), blk, 0, stream>>>(in_w, off_w, mask_w, out_w, dw_w,
                                              off_b, mask_b, in_h, hw_h, out_h,
                                              dwT, hbias);
        k_dwln<<<dim3(LL / 4), blk, 0, stream>>>(x, dwT, dw_b, ln_g, ln_b, x1h, xb);
        k_gemm_ih<<<dim3(256, 6), blk, 0, stream>>>(
            xb, x1h, in_h, hw_h, in_b, hbias, xpb, headb);
        k_gather<<<dim3(LL / 8), blk, 0, stream>>>(xpb, headb, rows);
        k_gemm_out<<<dim3(512, 2), blk, 0, stream>>>(rows, out_h, out_b, out);
    } else {
        float* xp = (float*)d_ws;   // 33.5 MB
        k_inproj_fb<<<dim3(LL), blk, 0, stream>>>(x, in_w, in_b, xp);
        k_main_fb<<<dim3(LL), blk, 0, stream>>>(x, xp, dw_w, dw_b, ln_g, ln_b,
                                                off_w, off_b, mask_w, mask_b,
                                                out_w, out_b, out);
    }
}

// Round 10
// 196.773 us; speedup vs baseline: 1.2538x; 1.0490x over previous
//
#include <hip/hip_runtime.h>

// DCNv3 forward, FP32 I/O. N=8, H=W=64, C=256, G=16, GC=16, K=3, P=9. L=32768.
//
// Round-20 (target: k_gemm_ih, measured 53us @ MfmaUtil 8.8%, Occ 19.8%):
//  - GEMM cores now 3-buffer counted-vmcnt pipelines: per K-step ONE fused
//    asm {s_waitcnt vmcnt(4); s_barrier} (waits only the oldest tile's
//    loads, next tile's stay in flight; fused asm prevents ds_read hoisting
//    past the barrier), then issue tile kt+2. Loads span 2 compute phases
//    instead of 1, and the fresh prefetch is never drained (__syncthreads
//    would force vmcnt(0)).
//  - headb row stride padded 432 -> 448 (896 B = sector-aligned): removes
//    ~2x write amplification seen in WRITE_SIZE (77 MB vs 45 useful).
//  - k_prep/k_dwln/k_gather = round-12 exact (proven). out-GEMM keeps BM=64.
// Dispatches: k_prep, k_dwln, k_gemm_ih, k_gather, k_gemm_out.
// Fallback: round-3 minimal path (33.5 MB) if ws too small.

#define LL 32768
#define CC 256
#define HSTR 448   // padded headb row stride (bf16 elems); 896 B, 64B-aligned

typedef __bf16 bf16;
typedef __bf16 bf16x4 __attribute__((ext_vector_type(4)));
typedef __bf16 bf16x8 __attribute__((ext_vector_type(8)));
typedef float f32x4v __attribute__((ext_vector_type(4)));
typedef float f32x2 __attribute__((ext_vector_type(2)));

__device__ __forceinline__ void gload16(const bf16* g, const bf16* lds_base) {
    __builtin_amdgcn_global_load_lds(
        (const __attribute__((address_space(1))) void*)g,
        (__attribute__((address_space(3))) void*)lds_base, 16, 0, 0);
}

// ---------------- weight prep: cvt + pack + pad, one launch ---------------
__global__ __launch_bounds__(256) void k_prep(
    const float* __restrict__ in_w, const float* __restrict__ off_w,
    const float* __restrict__ mask_w, const float* __restrict__ out_w,
    const float* __restrict__ dw_w, const float* __restrict__ off_b,
    const float* __restrict__ mask_b,
    bf16* __restrict__ in_h, bf16* __restrict__ hw_h,
    bf16* __restrict__ out_h,
    float* __restrict__ dwT, float* __restrict__ hbias) {
    int idx = blockIdx.x * 256 + threadIdx.x;
    if (idx < 60416) {
        const float* s; bf16* hi; int i;
        if (idx < 16384)      { s = in_w;   hi = in_h;          i = idx; }
        else if (idx < 34816) { s = off_w;  hi = hw_h;          i = idx - 16384; }
        else if (idx < 44032) { s = mask_w; hi = hw_h + 73728;  i = idx - 34816; }
        else                  { s = out_w;  hi = out_h;         i = idx - 44032; }
        float4 v = *(const float4*)(s + (size_t)i * 4);
        bf16x4 h;
        h[0] = (bf16)v.x; h[1] = (bf16)v.y; h[2] = (bf16)v.z; h[3] = (bf16)v.w;
        *(bf16x4*)(hi + (size_t)i * 4) = h;
    } else if (idx < 62720) {
        int e = idx - 60416;
        int c = e & 255, j = e >> 8;
        dwT[j * 256 + c] = dw_w[c * 9 + j];
    } else if (idx < 63232) {
        int e = idx - 62720;   // 0..511
        hbias[e] = (e < 288) ? off_b[e] : (e < 432 ? mask_b[e - 288] : 0.f);
    } else if (idx < 68352) {
        int e = idx - 63232;   // 0..5119 : zero-fill hw rows 432..511
        bf16x4 z = {(bf16)0.f, (bf16)0.f, (bf16)0.f, (bf16)0.f};
        *(bf16x4*)(hw_h + 110592 + (size_t)e * 4) = z;
    }
}

// ------- dwconv3x3 + LN + GELU (wave/pixel); also emits xb = bf16(x) ------
__global__ __launch_bounds__(256) void k_dwln(
    const float* __restrict__ x, const float* __restrict__ dwT,
    const float* __restrict__ dw_b, const float* __restrict__ ln_g,
    const float* __restrict__ ln_b, bf16* __restrict__ x1h,
    bf16* __restrict__ xb) {
    int t = threadIdx.x;
    int q = t >> 6, u = t & 63;
    int l = blockIdx.x * 4 + q;
    int w = l & 63, h = (l >> 6) & 63, n = l >> 12;
    int c0 = u * 4;

    float4 acc = *(const float4*)(dw_b + c0);
    float4 xc = {0.f, 0.f, 0.f, 0.f};
#pragma unroll
    for (int kh = 0; kh < 3; ++kh) {
        int hh = h + kh - 1;
        if (hh < 0 || hh >= 64) continue;
#pragma unroll
        for (int kw = 0; kw < 3; ++kw) {
            int ww = w + kw - 1;
            if (ww < 0 || ww >= 64) continue;
            float4 xv = *(const float4*)(x + (size_t)(((n * 64 + hh) * 64) + ww) * CC + c0);
            if (kh == 1 && kw == 1) xc = xv;
            float4 wv = *(const float4*)(dwT + (kh * 3 + kw) * 256 + c0);
            acc.x += xv.x * wv.x; acc.y += xv.y * wv.y;
            acc.z += xv.z * wv.z; acc.w += xv.w * wv.w;
        }
    }
    bf16x4 xcb;
    xcb[0] = (bf16)xc.x; xcb[1] = (bf16)xc.y;
    xcb[2] = (bf16)xc.z; xcb[3] = (bf16)xc.w;
    *(bf16x4*)(xb + (size_t)l * CC + c0) = xcb;

    float s = acc.x + acc.y + acc.z + acc.w;
    float ss = acc.x * acc.x + acc.y * acc.y + acc.z * acc.z + acc.w * acc.w;
#pragma unroll
    for (int d = 1; d < 64; d <<= 1) {
        s += __shfl_xor(s, d);
        ss += __shfl_xor(ss, d);
    }
    float mean = s * (1.0f / 256.0f);
    float var = ss * (1.0f / 256.0f) - mean * mean;
    float rstd = rsqrtf(var + 1e-6f);
    float4 gv = *(const float4*)(ln_g + c0);
    float4 bv = *(const float4*)(ln_b + c0);
    float xn0 = (acc.x - mean) * rstd * gv.x + bv.x;
    float xn1 = (acc.y - mean) * rstd * gv.y + bv.y;
    float xn2 = (acc.z - mean) * rstd * gv.z + bv.z;
    float xn3 = (acc.w - mean) * rstd * gv.w + bv.w;
    bf16x4 oh;
    oh[0] = (bf16)(0.5f * xn0 * (1.0f + erff(xn0 * 0.70710678118654752f)));
    oh[1] = (bf16)(0.5f * xn1 * (1.0f + erff(xn1 * 0.70710678118654752f)));
    oh[2] = (bf16)(0.5f * xn2 * (1.0f + erff(xn2 * 0.70710678118654752f)));
    oh[3] = (bf16)(0.5f * xn3 * (1.0f + erff(xn3 * 0.70710678118654752f)));
    *(bf16x4*)(x1h + (size_t)l * CC + c0) = oh;
}

// ---- 128x128-tile bf16 MFMA GEMM, 3-buffer counted-vmcnt pipeline --------
// C = A@W^T + bias (bf16 out, row stride cstride). K=256, BK=32.
// smem: 3 x 16 KB. Tile kt staged 2 iterations ahead; per-iter sync =
// fused {s_waitcnt vmcnt(4); s_barrier} (single asm: nothing can slip
// between wait and barrier, and memory clobber pins ds_reads below it).
__device__ __forceinline__ void gemm_core(
    const bf16* __restrict__ A, const bf16* __restrict__ Wh,
    const float* __restrict__ bias, bf16* __restrict__ Cbf,
    int Nout, int cstride, int mb, int nb) {
    int t = threadIdx.x, wave = t >> 6, lane = t & 63;
    int wm = wave & 1, wn = wave >> 1;
    int fm = lane & 15, fq = lane >> 4;

    __shared__ bf16 smem[24576];   // 3 bufs x 8192: [A 4096 | W 4096]

    const bf16* gbase[4];
    int lofs[4];
#pragma unroll
    for (int j = 0; j < 4; ++j) {
        int seg = wave * 4 + j;
        int arr = seg >> 3;
        int row = (seg & 7) * 16 + (lane >> 2);
        int col = (lane & 3) * 8;
        gbase[j] = (arr == 0) ? (A + (size_t)(mb + row) * CC + col)
                              : (Wh + (size_t)(nb + row) * CC + col);
        lofs[j] = seg * 512;
    }

    f32x4v acc[4][4];
#pragma unroll
    for (int i = 0; i < 4; ++i)
#pragma unroll
        for (int j = 0; j < 4; ++j) acc[i][j] = (f32x4v){0.f, 0.f, 0.f, 0.f};

    // prologue: stage tiles 0,1 into bufs 0,1 (8 loads/thread in flight)
#pragma unroll
    for (int j = 0; j < 4; ++j) gload16(gbase[j], smem + lofs[j]);
#pragma unroll
    for (int j = 0; j < 4; ++j) gload16(gbase[j] + 32, smem + 8192 + lofs[j]);

#pragma unroll
    for (int kt = 0; kt < 8; ++kt) {
        if (kt < 7)
            asm volatile("s_waitcnt vmcnt(4)\n\ts_barrier" ::: "memory");
        else
            asm volatile("s_waitcnt vmcnt(0)\n\ts_barrier" ::: "memory");
        if (kt < 6) {
#pragma unroll
            for (int j = 0; j < 4; ++j)
                gload16(gbase[j] + (kt + 2) * 32,
                        smem + ((kt + 2) % 3) * 8192 + lofs[j]);
        }
        const bf16* buf = smem + (kt % 3) * 8192;
        bf16x8 af[4], bfh[4];
#pragma unroll
        for (int i = 0; i < 4; ++i)
            af[i] = *(const bf16x8*)&buf[(wm * 64 + i * 16 + fm) * 32 + fq * 8];
#pragma unroll
        for (int j = 0; j < 4; ++j)
            bfh[j] = *(const bf16x8*)&buf[4096 + (wn * 64 + j * 16 + fm) * 32 + fq * 8];
#pragma unroll
        for (int i = 0; i < 4; ++i)
#pragma unroll
            for (int j = 0; j < 4; ++j)
                acc[i][j] = __builtin_amdgcn_mfma_f32_16x16x32_bf16(
                    af[i], bfh[j], acc[i][j], 0, 0, 0);
    }

    // D mapping: m = 16*tile + fq*4 + reg, n = 16*tile + fm
#pragma unroll
    for (int j = 0; j < 4; ++j) {
        int n_g = nb + wn * 64 + j * 16 + fm;
        if (n_g >= Nout) continue;
        float bv = bias[n_g];
#pragma unroll
        for (int i = 0; i < 4; ++i) {
            int m_g = mb + wm * 64 + i * 16 + fq * 4;
#pragma unroll
            for (int rg = 0; rg < 4; ++rg)
                Cbf[(size_t)(m_g + rg) * cstride + n_g] = (bf16)(acc[i][j][rg] + bv);
        }
    }
}

// Merged in-proj + head GEMM: grid (256, 6). y<2 -> in-proj (N=256),
// y>=2 -> offset/mask head (N=432, row stride HSTR=448).
__global__ __launch_bounds__(256) void k_gemm_ih(
    const bf16* __restrict__ xb, const bf16* __restrict__ x1h,
    const bf16* __restrict__ in_h, const bf16* __restrict__ hw_h,
    const float* __restrict__ in_b, const float* __restrict__ hbias,
    bf16* __restrict__ xpb, bf16* __restrict__ headb) {
    int mb = blockIdx.x * 128;
    int y = blockIdx.y;
    const bf16 *A, *W;
    const float* bs;
    bf16* Cb;
    int Nout, cstride, nb;
    if (y < 2) { A = xb;  W = in_h; bs = in_b;  Cb = xpb;   Nout = 256; cstride = 256;  nb = y * 128; }
    else       { A = x1h; W = hw_h; bs = hbias; Cb = headb; Nout = 432; cstride = HSTR; nb = (y - 2) * 128; }
    gemm_core(A, W, bs, Cb, Nout, cstride, mb, nb);
}

// ---- out-proj GEMM, BM=64, 3-buffer counted-vmcnt: C32 = A@W^T + bias ----
// grid (512, 2). smem: 3 x 12 KB = 36 KB -> 4 blocks/CU.
__global__ __launch_bounds__(256) void k_gemm_out(
    const bf16* __restrict__ A, const bf16* __restrict__ Wh,
    const float* __restrict__ bias, float* __restrict__ C32) {
    int mb = blockIdx.x * 64, nb = blockIdx.y * 128;
    int t = threadIdx.x, wave = t >> 6, lane = t & 63;
    int wm = wave & 1, wn = wave >> 1;
    int fm = lane & 15, fq = lane >> 4;

    __shared__ bf16 smem[18432];   // 3 bufs x 6144: [A 2048 | W 4096]

    const bf16* gbase[3];
    int lofs[3];
#pragma unroll
    for (int j = 0; j < 3; ++j) {
        int seg = wave * 3 + j;           // 0..11: segs 0-3 = A, 4-11 = W
        int r16 = (seg < 4) ? seg : (seg - 4);
        int row = r16 * 16 + (lane >> 2);
        int col = (lane & 3) * 8;
        gbase[j] = (seg < 4) ? (A + (size_t)(mb + row) * CC + col)
                             : (Wh + (size_t)(nb + row) * CC + col);
        lofs[j] = seg * 512;
    }

    f32x4v acc[2][4];
#pragma unroll
    for (int i = 0; i < 2; ++i)
#pragma unroll
        for (int j = 0; j < 4; ++j) acc[i][j] = (f32x4v){0.f, 0.f, 0.f, 0.f};

#pragma unroll
    for (int j = 0; j < 3; ++j) gload16(gbase[j], smem + lofs[j]);
#pragma unroll
    for (int j = 0; j < 3; ++j) gload16(gbase[j] + 32, smem + 6144 + lofs[j]);

#pragma unroll
    for (int kt = 0; kt < 8; ++kt) {
        if (kt < 7)
            asm volatile("s_waitcnt vmcnt(3)\n\ts_barrier" ::: "memory");
        else
            asm volatile("s_waitcnt vmcnt(0)\n\ts_barrier" ::: "memory");
        if (kt < 6) {
#pragma unroll
            for (int j = 0; j < 3; ++j)
                gload16(gbase[j] + (kt + 2) * 32,
                        smem + ((kt + 2) % 3) * 6144 + lofs[j]);
        }
        const bf16* buf = smem + (kt % 3) * 6144;
        bf16x8 af[2], bfh[4];
#pragma unroll
        for (int i = 0; i < 2; ++i)
            af[i] = *(const bf16x8*)&buf[(wm * 32 + i * 16 + fm) * 32 + fq * 8];
#pragma unroll
        for (int j = 0; j < 4; ++j)
            bfh[j] = *(const bf16x8*)&buf[2048 + (wn * 64 + j * 16 + fm) * 32 + fq * 8];
#pragma unroll
        for (int i = 0; i < 2; ++i)
#pragma unroll
            for (int j = 0; j < 4; ++j)
                acc[i][j] = __builtin_amdgcn_mfma_f32_16x16x32_bf16(
                    af[i], bfh[j], acc[i][j], 0, 0, 0);
    }

#pragma unroll
    for (int j = 0; j < 4; ++j) {
        int n_g = nb + wn * 64 + j * 16 + fm;
        float bv = bias[n_g];
#pragma unroll
        for (int i = 0; i < 2; ++i) {
            int m_g = mb + wm * 32 + i * 16 + fq * 4;
#pragma unroll
            for (int rg = 0; rg < 4; ++rg)
                C32[(size_t)(m_g + rg) * 256 + n_g] = acc[i][j][rg] + bv;
        }
    }
}

// ------ softmax + bilinear gather (8 ch/thread) — round-12 exact ----------
// (head row stride = HSTR)
__device__ __forceinline__ void mac8(f32x2 acc[4], bf16x8 v, float wt) {
    union { bf16x8 b; unsigned u[4]; } cu;
    cu.b = v;
    f32x2 wv = {wt, wt};
#pragma unroll
    for (int i = 0; i < 4; ++i) {
        f32x2 a;
        a.x = __uint_as_float(cu.u[i] << 16);          // bf16 lo -> f32 exact
        a.y = __uint_as_float(cu.u[i] & 0xffff0000u);  // bf16 hi -> f32 exact
        acc[i] += a * wv;                              // contracts to pk fma
    }
}

__global__ __launch_bounds__(256) void k_gather(
    const bf16* __restrict__ xp, const bf16* __restrict__ head,
    bf16* __restrict__ rows) {
    int t = threadIdx.x;
    int q = t >> 5, u = t & 31;
    int l = blockIdx.x * 8 + q;
    int w = l & 63, h = (l >> 6) & 63, n = l >> 12;

    __shared__ float CW[8][576];   // stage: [0,288)=offs [288,432)=mask
    __shared__ int BASE[8][144];   // weights phase: CW[e*4..]=cw4, BASE[e]=idx

    for (int j = u; j < 432; j += 32) CW[q][j] = (float)head[(size_t)l * HSTR + j];
    __syncthreads();

    if (u < 16) {
        int g = u;
        float mx = -1e30f;
#pragma unroll
        for (int p = 0; p < 9; ++p) mx = fmaxf(mx, CW[q][288 + g * 9 + p]);
        float s = 0.f, e[9];
#pragma unroll
        for (int p = 0; p < 9; ++p) { e[p] = expf(CW[q][288 + g * 9 + p] - mx); s += e[p]; }
        float inv = 1.0f / s;
#pragma unroll
        for (int p = 0; p < 9; ++p) CW[q][288 + g * 9 + p] = e[p] * inv;
    }
    __syncthreads();

    // phase 3: 144 (g,p) pairs / 32 threads: e = u, u+32, u+64, u+96, (u<16: u+128)
    float4 cwr[5];
    int baser[5];
#pragma unroll
    for (int k = 0; k < 5; ++k) {
        if (k < 4 || u < 16) {
            int ei = u + 32 * k;
            int g = ei / 9, p = ei - g * 9;
            float ox = CW[q][g * 18 + p * 2 + 0];
            float oy = CW[q][g * 18 + p * 2 + 1];
            float m  = CW[q][288 + ei];
            float ax = (float)(w + (p / 3) - 1) + ox;
            float ay = (float)(h + (p % 3) - 1) + oy;
            float x0f = floorf(ax), y0f = floorf(ay);
            int x0 = (int)x0f, y0 = (int)y0f;
            float tx = ax - x0f, ty = ay - y0f;
            int xb, yb;
            float wxa, wxb, wya, wyb;
            if (x0 < 0)       { xb = 0;  wxa = (x0 == -1) ? tx : 0.f; wxb = 0.f; }
            else if (x0 > 62) { xb = 62; wxa = 0.f; wxb = (x0 == 63) ? (1.f - tx) : 0.f; }
            else              { xb = x0; wxa = 1.f - tx; wxb = tx; }
            if (y0 < 0)       { yb = 0;  wya = (y0 == -1) ? ty : 0.f; wyb = 0.f; }
            else if (y0 > 62) { yb = 62; wya = 0.f; wyb = (y0 == 63) ? (1.f - ty) : 0.f; }
            else              { yb = y0; wya = 1.f - ty; wyb = ty; }
            float4 cw;
            cw.x = m * wxa * wya; cw.y = m * wxb * wya;
            cw.z = m * wxa * wyb; cw.w = m * wxb * wyb;
            cwr[k] = cw;
            baser[k] = (n << 20) + (yb * 64 + xb) * 256;
        }
    }
    __syncthreads();   // all offs/mask reads done before overwriting CW
#pragma unroll
    for (int k = 0; k < 5; ++k) {
        if (k < 4 || u < 16) {
            int ei = u + 32 * k;
            *(float4*)&CW[q][ei * 4] = cwr[k];
            BASE[q][ei] = baser[k];
        }
    }
    __syncthreads();

    // phase 4: sampling
    int g = u >> 1;
    int c0 = g * 16 + (u & 1) * 8;
    const bf16* xpc = xp + c0;
    f32x2 acc[4];
    acc[0] = (f32x2){0.f, 0.f}; acc[1] = (f32x2){0.f, 0.f};
    acc[2] = (f32x2){0.f, 0.f}; acc[3] = (f32x2){0.f, 0.f};
#pragma unroll
    for (int p = 0; p < 9; ++p) {
        int ei = g * 9 + p;
        float4 cw = *(const float4*)&CW[q][ei * 4];
        int base = BASE[q][ei];
        const bf16* p0 = xpc + base;
        const bf16* p1 = p0 + 16384;          // +1 row (64*256)
        bf16x8 v00 = *(const bf16x8*)(p0);
        bf16x8 v01 = *(const bf16x8*)(p0 + 256);
        bf16x8 v10 = *(const bf16x8*)(p1);
        bf16x8 v11 = *(const bf16x8*)(p1 + 256);
        mac8(acc, v00, cw.x);
        mac8(acc, v01, cw.y);
        mac8(acc, v10, cw.z);
        mac8(acc, v11, cw.w);
    }
    bf16x8 oh;
    oh[0] = (bf16)acc[0].x; oh[1] = (bf16)acc[0].y;
    oh[2] = (bf16)acc[1].x; oh[3] = (bf16)acc[1].y;
    oh[4] = (bf16)acc[2].x; oh[5] = (bf16)acc[2].y;
    oh[6] = (bf16)acc[3].x; oh[7] = (bf16)acc[3].y;
    *(bf16x8*)(rows + (size_t)l * CC + c0) = oh;
}

// ======================= round-3 minimal fallback =========================
__device__ __forceinline__ float dot256f(const float* a, const float* wrow) {
    const float4* w4 = (const float4*)wrow;
    float s = 0.f;
#pragma unroll 16
    for (int i = 0; i < 64; ++i) {
        float4 u = w4[i];
        const float* ap = a + i * 4;
        s += ap[0] * u.x + ap[1] * u.y + ap[2] * u.z + ap[3] * u.w;
    }
    return s;
}

__global__ __launch_bounds__(256) void k_inproj_fb(
    const float* __restrict__ x, const float* __restrict__ in_w,
    const float* __restrict__ in_b, float* __restrict__ xp) {
    int l = blockIdx.x;
    int t = threadIdx.x;
    __shared__ float xa[256];
    xa[t] = x[l * CC + t];
    __syncthreads();
    xp[l * CC + t] = dot256f(xa, in_w + t * CC) + in_b[t];
}

__device__ __forceinline__ float fetch_px_fb(const float* base, int yy, int xx) {
    if (xx < 0 || xx >= 64 || yy < 0 || yy >= 64) return 0.f;
    return base[(yy * 64 + xx) * CC];
}

__global__ __launch_bounds__(256) void k_main_fb(
    const float* __restrict__ x, const float* __restrict__ xp,
    const float* __restrict__ dw_w, const float* __restrict__ dw_b,
    const float* __restrict__ ln_g, const float* __restrict__ ln_b,
    const float* __restrict__ off_w, const float* __restrict__ off_b,
    const float* __restrict__ mask_w, const float* __restrict__ mask_b,
    const float* __restrict__ out_w, const float* __restrict__ out_b,
    float* __restrict__ out) {
    int l = blockIdx.x;
    int t = threadIdx.x;
    int w = l & 63, h = (l >> 6) & 63, n = l >> 12;
    __shared__ float x1[256];
    __shared__ float red[256];
    __shared__ float offs[288];
    __shared__ float ms[144];
    __shared__ float row[256];

    float acc = dw_b[t];
#pragma unroll
    for (int kh = 0; kh < 3; ++kh) {
        int hh = h + kh - 1;
        if (hh < 0 || hh >= 64) continue;
#pragma unroll
        for (int kw = 0; kw < 3; ++kw) {
            int ww = w + kw - 1;
            if (ww < 0 || ww >= 64) continue;
            acc += x[(((n * 64 + hh) * 64) + ww) * CC + t] * dw_w[t * 9 + kh * 3 + kw];
        }
    }
    red[t] = acc;
    __syncthreads();
    for (int s = 128; s > 0; s >>= 1) {
        if (t < s) red[t] += red[t + s];
        __syncthreads();
    }
    float mean = red[0] * (1.0f / 256.0f);
    __syncthreads();
    float d = acc - mean;
    red[t] = d * d;
    __syncthreads();
    for (int s = 128; s > 0; s >>= 1) {
        if (t < s) red[t] += red[t + s];
        __syncthreads();
    }
    float var = red[0] * (1.0f / 256.0f);
    float xn = d * rsqrtf(var + 1e-6f) * ln_g[t] + ln_b[t];
    x1[t] = 0.5f * xn * (1.0f + erff(xn * 0.70710678118654752f));
    __syncthreads();

    offs[t] = dot256f(x1, off_w + t * CC) + off_b[t];
    if (t < 32) {
        int j = 256 + t;
        offs[j] = dot256f(x1, off_w + j * CC) + off_b[j];
    }
    if (t < 144) ms[t] = dot256f(x1, mask_w + t * CC) + mask_b[t];
    __syncthreads();

    if (t < 16) {
        int g = t;
        float mx = -1e30f;
#pragma unroll
        for (int p = 0; p < 9; ++p) mx = fmaxf(mx, ms[g * 9 + p]);
        float s = 0.f, e[9];
#pragma unroll
        for (int p = 0; p < 9; ++p) { e[p] = expf(ms[g * 9 + p] - mx); s += e[p]; }
        float inv = 1.0f / s;
#pragma unroll
        for (int p = 0; p < 9; ++p) ms[g * 9 + p] = e[p] * inv;
    }
    __syncthreads();

    int g = t >> 4;
    const float* base = xp + (size_t)n * 64 * 64 * CC + t;
    float acc2 = 0.f;
#pragma unroll
    for (int p = 0; p < 9; ++p) {
        float ox = offs[g * 18 + p * 2 + 0];
        float oy = offs[g * 18 + p * 2 + 1];
        float ax = (float)(w + (p / 3) - 1) + ox;
        float ay = (float)(h + (p % 3) - 1) + oy;
        float x0f = floorf(ax), y0f = floorf(ay);
        int x0 = (int)x0f, y0 = (int)y0f;
        float tx = ax - x0f, ty = ay - y0f;
        float v00 = fetch_px_fb(base, y0, x0);
        float v01 = fetch_px_fb(base, y0, x0 + 1);
        float v10 = fetch_px_fb(base, y0 + 1, x0);
        float v11 = fetch_px_fb(base, y0 + 1, x0 + 1);
        float bl = (v00 * (1.f - tx) + v01 * tx) * (1.f - ty) +
                   (v10 * (1.f - tx) + v11 * tx) * ty;
        acc2 += ms[g * 9 + p] * bl;
    }
    row[t] = acc2;
    __syncthreads();
    out[l * CC + t] = dot256f(row, out_w + t * CC) + out_b[t];
}

// ==========================================================================
extern "C" void kernel_launch(void* const* d_in, const int* in_sizes, int n_in,
                              void* d_out, int out_size, void* d_ws,
                              size_t ws_size, hipStream_t stream) {
    const float* x      = (const float*)d_in[0];
    const float* dw_w   = (const float*)d_in[1];
    const float* dw_b   = (const float*)d_in[2];
    const float* ln_g   = (const float*)d_in[3];
    const float* ln_b   = (const float*)d_in[4];
    const float* off_w  = (const float*)d_in[5];
    const float* off_b  = (const float*)d_in[6];
    const float* mask_w = (const float*)d_in[7];
    const float* mask_b = (const float*)d_in[8];
    const float* in_w   = (const float*)d_in[9];
    const float* in_b   = (const float*)d_in[10];
    const float* out_w  = (const float*)d_in[11];
    const float* out_b  = (const float*)d_in[12];
    float* out = (float*)d_out;

    const size_t szBF    = (size_t)LL * CC * 2;     // 16,777,216
    const size_t szHEADB = (size_t)LL * HSTR * 2;   // 29,360,128 (padded)
    const size_t szWB    = 1048576;                 // weight blob
    const size_t need    = 3 * szBF + szHEADB + szWB;  // ~81 MB

    dim3 blk(256);
    if (ws_size >= need) {
        char* p = (char*)d_ws;
        bf16* x1h = (bf16*)p; p += szBF;       // reused as rows after head GEMM
        bf16* xpb = (bf16*)p; p += szBF;
        bf16* xb  = (bf16*)p; p += szBF;
        bf16* headb = (bf16*)p; p += szHEADB;
        bf16* in_h  = (bf16*)p; p += 131072;
        bf16* hw_h  = (bf16*)p; p += 262144;   // 512 x 256 bf16 (rows 432+ zeroed)
        bf16* out_h = (bf16*)p; p += 131072;
        float* dwT  = (float*)p; p += 9216;
        float* hbias = (float*)p;
        bf16* rows = x1h;

        k_prep<<<dim3(267), blk, 0, stream>>>(in_w, off_w, mask_w, out_w, dw_w,
                                              off_b, mask_b, in_h, hw_h, out_h,
                                              dwT, hbias);
        k_dwln<<<dim3(LL / 4), blk, 0, stream>>>(x, dwT, dw_b, ln_g, ln_b, x1h, xb);
        k_gemm_ih<<<dim3(256, 6), blk, 0, stream>>>(
            xb, x1h, in_h, hw_h, in_b, hbias, xpb, headb);
        k_gather<<<dim3(LL / 8), blk, 0, stream>>>(xpb, headb, rows);
        k_gemm_out<<<dim3(512, 2), blk, 0, stream>>>(rows, out_h, out_b, out);
    } else {
        float* xp = (float*)d_ws;   // 33.5 MB
        k_inproj_fb<<<dim3(LL), blk, 0, stream>>>(x, in_w, in_b, xp);
        k_main_fb<<<dim3(LL), blk, 0, stream>>>(x, xp, dw_w, dw_b, ln_g, ln_b,
                                                off_w, off_b, mask_w, mask_b,
                                                out_w, out_b, out);
    }
}

// Round 11
// 190.244 us; speedup vs baseline: 1.2969x; 1.0343x over previous
//
#include <hip/hip_runtime.h>

// DCNv3 forward, FP32 I/O. N=8, H=W=64, C=256, G=16, GC=16, K=3, P=9. L=32768.
//
// Round-21 (on round-20's 196.8us best):
//  - k_prep re-merged into k_dwln (k_dwp, grid 8450; prep = blocks 8192+).
//    R18's regression was the UNCOALESCED direct dw_w reads, not the merge:
//    now each dwln block stages dw_w (9 KB) into LDS once via coalesced
//    float4 loads + transposed scatter (wlds[j*256+c]), so tap reads are
//    the same coalesced float4 pattern as the proven dwT version.
//    Saves the k_prep dispatch + gap. 5 -> 4 dispatches.
//  - k_gather head staging vectorized: 2x bf16x8 loads/thread (HSTR=448
//    rows are 16B-aligned) instead of 14 scalar bf16 loads.
//  - GEMMs unchanged from round-20 (3-buffer counted-vmcnt, validated).
// Dispatches: k_dwp, k_gemm_ih, k_gather, k_gemm_out.
// Fallback: round-3 minimal path (33.5 MB) if ws too small.

#define LL 32768
#define CC 256
#define HSTR 448   // padded headb row stride (bf16 elems); 896 B, 64B-aligned

typedef __bf16 bf16;
typedef __bf16 bf16x4 __attribute__((ext_vector_type(4)));
typedef __bf16 bf16x8 __attribute__((ext_vector_type(8)));
typedef float f32x4v __attribute__((ext_vector_type(4)));
typedef float f32x2 __attribute__((ext_vector_type(2)));

__device__ __forceinline__ void gload16(const bf16* g, const bf16* lds_base) {
    __builtin_amdgcn_global_load_lds(
        (const __attribute__((address_space(1))) void*)g,
        (__attribute__((address_space(3))) void*)lds_base, 16, 0, 0);
}

// ------- merged: dwconv3x3 + LN + GELU (blocks 0..8191) | prep (8192+) ----
__global__ __launch_bounds__(256) void k_dwp(
    const float* __restrict__ x, const float* __restrict__ dw_w,
    const float* __restrict__ dw_b, const float* __restrict__ ln_g,
    const float* __restrict__ ln_b, bf16* __restrict__ x1h,
    bf16* __restrict__ xb,
    const float* __restrict__ in_w, const float* __restrict__ off_w,
    const float* __restrict__ mask_w, const float* __restrict__ out_w,
    const float* __restrict__ off_b, const float* __restrict__ mask_b,
    bf16* __restrict__ in_h, bf16* __restrict__ hw_h,
    bf16* __restrict__ out_h, float* __restrict__ hbias) {
    int t = threadIdx.x;
    int b = blockIdx.x;
    if (b >= 8192) {
        // ---------------- weight prep: cvt + pack + pad -------------------
        int idx = (b - 8192) * 256 + t;
        if (idx < 60416) {
            const float* s; bf16* hi; int i;
            if (idx < 16384)      { s = in_w;   hi = in_h;          i = idx; }
            else if (idx < 34816) { s = off_w;  hi = hw_h;          i = idx - 16384; }
            else if (idx < 44032) { s = mask_w; hi = hw_h + 73728;  i = idx - 34816; }
            else                  { s = out_w;  hi = out_h;         i = idx - 44032; }
            float4 v = *(const float4*)(s + (size_t)i * 4);
            bf16x4 hh;
            hh[0] = (bf16)v.x; hh[1] = (bf16)v.y; hh[2] = (bf16)v.z; hh[3] = (bf16)v.w;
            *(bf16x4*)(hi + (size_t)i * 4) = hh;
        } else if (idx < 60928) {
            int e = idx - 60416;   // 0..511
            hbias[e] = (e < 288) ? off_b[e] : (e < 432 ? mask_b[e - 288] : 0.f);
        } else if (idx < 66048) {
            int e = idx - 60928;   // 0..5119 : zero-fill hw rows 432..511
            bf16x4 z = {(bf16)0.f, (bf16)0.f, (bf16)0.f, (bf16)0.f};
            *(bf16x4*)(hw_h + 110592 + (size_t)e * 4) = z;
        }
        return;
    }
    // ------------------- dwconv3x3 + LN + GELU (wave/pixel) ---------------
    // Stage dw_w transposed in LDS once per block (coalesced float4 loads,
    // scatter ds_writes): tap reads become the proven coalesced pattern.
    __shared__ float wlds[2304];   // [j=0..8][c=0..255]
    for (int i4 = t; i4 < 576; i4 += 256) {
        float4 v = *(const float4*)(dw_w + i4 * 4);
        int e = i4 * 4;
#pragma unroll
        for (int k = 0; k < 4; ++k) {
            int ee = e + k;
            int c = ee / 9;
            int j = ee - c * 9;
            wlds[j * 256 + c] = v[k];
        }
    }
    __syncthreads();

    int q = t >> 6, u = t & 63;
    int l = b * 4 + q;
    int w = l & 63, h = (l >> 6) & 63, n = l >> 12;
    int c0 = u * 4;

    float4 acc = *(const float4*)(dw_b + c0);
    float4 xc = {0.f, 0.f, 0.f, 0.f};
#pragma unroll
    for (int kh = 0; kh < 3; ++kh) {
        int hh = h + kh - 1;
        if (hh < 0 || hh >= 64) continue;
#pragma unroll
        for (int kw = 0; kw < 3; ++kw) {
            int ww = w + kw - 1;
            if (ww < 0 || ww >= 64) continue;
            float4 xv = *(const float4*)(x + (size_t)(((n * 64 + hh) * 64) + ww) * CC + c0);
            if (kh == 1 && kw == 1) xc = xv;
            float4 wv = *(const float4*)&wlds[(kh * 3 + kw) * 256 + c0];
            acc.x += xv.x * wv.x; acc.y += xv.y * wv.y;
            acc.z += xv.z * wv.z; acc.w += xv.w * wv.w;
        }
    }
    bf16x4 xcb;
    xcb[0] = (bf16)xc.x; xcb[1] = (bf16)xc.y;
    xcb[2] = (bf16)xc.z; xcb[3] = (bf16)xc.w;
    *(bf16x4*)(xb + (size_t)l * CC + c0) = xcb;

    float s = acc.x + acc.y + acc.z + acc.w;
    float ss = acc.x * acc.x + acc.y * acc.y + acc.z * acc.z + acc.w * acc.w;
#pragma unroll
    for (int d = 1; d < 64; d <<= 1) {
        s += __shfl_xor(s, d);
        ss += __shfl_xor(ss, d);
    }
    float mean = s * (1.0f / 256.0f);
    float var = ss * (1.0f / 256.0f) - mean * mean;
    float rstd = rsqrtf(var + 1e-6f);
    float4 gv = *(const float4*)(ln_g + c0);
    float4 bv = *(const float4*)(ln_b + c0);
    float xn0 = (acc.x - mean) * rstd * gv.x + bv.x;
    float xn1 = (acc.y - mean) * rstd * gv.y + bv.y;
    float xn2 = (acc.z - mean) * rstd * gv.z + bv.z;
    float xn3 = (acc.w - mean) * rstd * gv.w + bv.w;
    bf16x4 oh;
    oh[0] = (bf16)(0.5f * xn0 * (1.0f + erff(xn0 * 0.70710678118654752f)));
    oh[1] = (bf16)(0.5f * xn1 * (1.0f + erff(xn1 * 0.70710678118654752f)));
    oh[2] = (bf16)(0.5f * xn2 * (1.0f + erff(xn2 * 0.70710678118654752f)));
    oh[3] = (bf16)(0.5f * xn3 * (1.0f + erff(xn3 * 0.70710678118654752f)));
    *(bf16x4*)(x1h + (size_t)l * CC + c0) = oh;
}

// ---- 128x128-tile bf16 MFMA GEMM, 3-buffer counted-vmcnt pipeline --------
// C = A@W^T + bias (bf16 out, row stride cstride). K=256, BK=32.
__device__ __forceinline__ void gemm_core(
    const bf16* __restrict__ A, const bf16* __restrict__ Wh,
    const float* __restrict__ bias, bf16* __restrict__ Cbf,
    int Nout, int cstride, int mb, int nb) {
    int t = threadIdx.x, wave = t >> 6, lane = t & 63;
    int wm = wave & 1, wn = wave >> 1;
    int fm = lane & 15, fq = lane >> 4;

    __shared__ bf16 smem[24576];   // 3 bufs x 8192: [A 4096 | W 4096]

    const bf16* gbase[4];
    int lofs[4];
#pragma unroll
    for (int j = 0; j < 4; ++j) {
        int seg = wave * 4 + j;
        int arr = seg >> 3;
        int row = (seg & 7) * 16 + (lane >> 2);
        int col = (lane & 3) * 8;
        gbase[j] = (arr == 0) ? (A + (size_t)(mb + row) * CC + col)
                              : (Wh + (size_t)(nb + row) * CC + col);
        lofs[j] = seg * 512;
    }

    f32x4v acc[4][4];
#pragma unroll
    for (int i = 0; i < 4; ++i)
#pragma unroll
        for (int j = 0; j < 4; ++j) acc[i][j] = (f32x4v){0.f, 0.f, 0.f, 0.f};

    // prologue: stage tiles 0,1 into bufs 0,1 (8 loads/thread in flight)
#pragma unroll
    for (int j = 0; j < 4; ++j) gload16(gbase[j], smem + lofs[j]);
#pragma unroll
    for (int j = 0; j < 4; ++j) gload16(gbase[j] + 32, smem + 8192 + lofs[j]);

#pragma unroll
    for (int kt = 0; kt < 8; ++kt) {
        if (kt < 7)
            asm volatile("s_waitcnt vmcnt(4)\n\ts_barrier" ::: "memory");
        else
            asm volatile("s_waitcnt vmcnt(0)\n\ts_barrier" ::: "memory");
        if (kt < 6) {
#pragma unroll
            for (int j = 0; j < 4; ++j)
                gload16(gbase[j] + (kt + 2) * 32,
                        smem + ((kt + 2) % 3) * 8192 + lofs[j]);
        }
        const bf16* buf = smem + (kt % 3) * 8192;
        bf16x8 af[4], bfh[4];
#pragma unroll
        for (int i = 0; i < 4; ++i)
            af[i] = *(const bf16x8*)&buf[(wm * 64 + i * 16 + fm) * 32 + fq * 8];
#pragma unroll
        for (int j = 0; j < 4; ++j)
            bfh[j] = *(const bf16x8*)&buf[4096 + (wn * 64 + j * 16 + fm) * 32 + fq * 8];
#pragma unroll
        for (int i = 0; i < 4; ++i)
#pragma unroll
            for (int j = 0; j < 4; ++j)
                acc[i][j] = __builtin_amdgcn_mfma_f32_16x16x32_bf16(
                    af[i], bfh[j], acc[i][j], 0, 0, 0);
    }

    // D mapping: m = 16*tile + fq*4 + reg, n = 16*tile + fm
#pragma unroll
    for (int j = 0; j < 4; ++j) {
        int n_g = nb + wn * 64 + j * 16 + fm;
        if (n_g >= Nout) continue;
        float bv = bias[n_g];
#pragma unroll
        for (int i = 0; i < 4; ++i) {
            int m_g = mb + wm * 64 + i * 16 + fq * 4;
#pragma unroll
            for (int rg = 0; rg < 4; ++rg)
                Cbf[(size_t)(m_g + rg) * cstride + n_g] = (bf16)(acc[i][j][rg] + bv);
        }
    }
}

// Merged in-proj + head GEMM: grid (256, 6). y<2 -> in-proj (N=256),
// y>=2 -> offset/mask head (N=432, row stride HSTR=448).
__global__ __launch_bounds__(256) void k_gemm_ih(
    const bf16* __restrict__ xb, const bf16* __restrict__ x1h,
    const bf16* __restrict__ in_h, const bf16* __restrict__ hw_h,
    const float* __restrict__ in_b, const float* __restrict__ hbias,
    bf16* __restrict__ xpb, bf16* __restrict__ headb) {
    int mb = blockIdx.x * 128;
    int y = blockIdx.y;
    const bf16 *A, *W;
    const float* bs;
    bf16* Cb;
    int Nout, cstride, nb;
    if (y < 2) { A = xb;  W = in_h; bs = in_b;  Cb = xpb;   Nout = 256; cstride = 256;  nb = y * 128; }
    else       { A = x1h; W = hw_h; bs = hbias; Cb = headb; Nout = 432; cstride = HSTR; nb = (y - 2) * 128; }
    gemm_core(A, W, bs, Cb, Nout, cstride, mb, nb);
}

// ---- out-proj GEMM, BM=64, 3-buffer counted-vmcnt: C32 = A@W^T + bias ----
// grid (512, 2). smem: 3 x 12 KB = 36 KB -> 4 blocks/CU.
__global__ __launch_bounds__(256) void k_gemm_out(
    const bf16* __restrict__ A, const bf16* __restrict__ Wh,
    const float* __restrict__ bias, float* __restrict__ C32) {
    int mb = blockIdx.x * 64, nb = blockIdx.y * 128;
    int t = threadIdx.x, wave = t >> 6, lane = t & 63;
    int wm = wave & 1, wn = wave >> 1;
    int fm = lane & 15, fq = lane >> 4;

    __shared__ bf16 smem[18432];   // 3 bufs x 6144: [A 2048 | W 4096]

    const bf16* gbase[3];
    int lofs[3];
#pragma unroll
    for (int j = 0; j < 3; ++j) {
        int seg = wave * 3 + j;           // 0..11: segs 0-3 = A, 4-11 = W
        int r16 = (seg < 4) ? seg : (seg - 4);
        int row = r16 * 16 + (lane >> 2);
        int col = (lane & 3) * 8;
        gbase[j] = (seg < 4) ? (A + (size_t)(mb + row) * CC + col)
                             : (Wh + (size_t)(nb + row) * CC + col);
        lofs[j] = seg * 512;
    }

    f32x4v acc[2][4];
#pragma unroll
    for (int i = 0; i < 2; ++i)
#pragma unroll
        for (int j = 0; j < 4; ++j) acc[i][j] = (f32x4v){0.f, 0.f, 0.f, 0.f};

#pragma unroll
    for (int j = 0; j < 3; ++j) gload16(gbase[j], smem + lofs[j]);
#pragma unroll
    for (int j = 0; j < 3; ++j) gload16(gbase[j] + 32, smem + 6144 + lofs[j]);

#pragma unroll
    for (int kt = 0; kt < 8; ++kt) {
        if (kt < 7)
            asm volatile("s_waitcnt vmcnt(3)\n\ts_barrier" ::: "memory");
        else
            asm volatile("s_waitcnt vmcnt(0)\n\ts_barrier" ::: "memory");
        if (kt < 6) {
#pragma unroll
            for (int j = 0; j < 3; ++j)
                gload16(gbase[j] + (kt + 2) * 32,
                        smem + ((kt + 2) % 3) * 6144 + lofs[j]);
        }
        const bf16* buf = smem + (kt % 3) * 6144;
        bf16x8 af[2], bfh[4];
#pragma unroll
        for (int i = 0; i < 2; ++i)
            af[i] = *(const bf16x8*)&buf[(wm * 32 + i * 16 + fm) * 32 + fq * 8];
#pragma unroll
        for (int j = 0; j < 4; ++j)
            bfh[j] = *(const bf16x8*)&buf[2048 + (wn * 64 + j * 16 + fm) * 32 + fq * 8];
#pragma unroll
        for (int i = 0; i < 2; ++i)
#pragma unroll
            for (int j = 0; j < 4; ++j)
                acc[i][j] = __builtin_amdgcn_mfma_f32_16x16x32_bf16(
                    af[i], bfh[j], acc[i][j], 0, 0, 0);
    }

#pragma unroll
    for (int j = 0; j < 4; ++j) {
        int n_g = nb + wn * 64 + j * 16 + fm;
        float bv = bias[n_g];
#pragma unroll
        for (int i = 0; i < 2; ++i) {
            int m_g = mb + wm * 32 + i * 16 + fq * 4;
#pragma unroll
            for (int rg = 0; rg < 4; ++rg)
                C32[(size_t)(m_g + rg) * 256 + n_g] = acc[i][j][rg] + bv;
        }
    }
}

// ------ softmax + bilinear gather (8 ch/thread) ---------------------------
// Round-12 core; head staging vectorized (bf16x8, HSTR rows 16B-aligned).
__device__ __forceinline__ void mac8(f32x2 acc[4], bf16x8 v, float wt) {
    union { bf16x8 b; unsigned u[4]; } cu;
    cu.b = v;
    f32x2 wv = {wt, wt};
#pragma unroll
    for (int i = 0; i < 4; ++i) {
        f32x2 a;
        a.x = __uint_as_float(cu.u[i] << 16);          // bf16 lo -> f32 exact
        a.y = __uint_as_float(cu.u[i] & 0xffff0000u);  // bf16 hi -> f32 exact
        acc[i] += a * wv;                              // contracts to pk fma
    }
}

__global__ __launch_bounds__(256) void k_gather(
    const bf16* __restrict__ xp, const bf16* __restrict__ head,
    bf16* __restrict__ rows) {
    int t = threadIdx.x;
    int q = t >> 5, u = t & 31;
    int l = blockIdx.x * 8 + q;
    int w = l & 63, h = (l >> 6) & 63, n = l >> 12;

    __shared__ float CW[8][576];   // stage: [0,288)=offs [288,432)=mask
    __shared__ int BASE[8][144];   // weights phase: CW[e*4..]=cw4, BASE[e]=idx

#pragma unroll
    for (int k = 0; k < 2; ++k) {
        int cj = u + 27 * k;
        if (u < 27) {
            bf16x8 v = *(const bf16x8*)(head + (size_t)l * HSTR + cj * 8);
            float4 f0, f1;
            f0.x = (float)v[0]; f0.y = (float)v[1]; f0.z = (float)v[2]; f0.w = (float)v[3];
            f1.x = (float)v[4]; f1.y = (float)v[5]; f1.z = (float)v[6]; f1.w = (float)v[7];
            *(float4*)&CW[q][cj * 8] = f0;
            *(float4*)&CW[q][cj * 8 + 4] = f1;
        }
    }
    __syncthreads();

    if (u < 16) {
        int g = u;
        float mx = -1e30f;
#pragma unroll
        for (int p = 0; p < 9; ++p) mx = fmaxf(mx, CW[q][288 + g * 9 + p]);
        float s = 0.f, e[9];
#pragma unroll
        for (int p = 0; p < 9; ++p) { e[p] = expf(CW[q][288 + g * 9 + p] - mx); s += e[p]; }
        float inv = 1.0f / s;
#pragma unroll
        for (int p = 0; p < 9; ++p) CW[q][288 + g * 9 + p] = e[p] * inv;
    }
    __syncthreads();

    // phase 3: 144 (g,p) pairs / 32 threads: e = u, u+32, u+64, u+96, (u<16: u+128)
    float4 cwr[5];
    int baser[5];
#pragma unroll
    for (int k = 0; k < 5; ++k) {
        if (k < 4 || u < 16) {
            int ei = u + 32 * k;
            int g = ei / 9, p = ei - g * 9;
            float ox = CW[q][g * 18 + p * 2 + 0];
            float oy = CW[q][g * 18 + p * 2 + 1];
            float m  = CW[q][288 + ei];
            float ax = (float)(w + (p / 3) - 1) + ox;
            float ay = (float)(h + (p % 3) - 1) + oy;
            float x0f = floorf(ax), y0f = floorf(ay);
            int x0 = (int)x0f, y0 = (int)y0f;
            float tx = ax - x0f, ty = ay - y0f;
            int xb, yb;
            float wxa, wxb, wya, wyb;
            if (x0 < 0)       { xb = 0;  wxa = (x0 == -1) ? tx : 0.f; wxb = 0.f; }
            else if (x0 > 62) { xb = 62; wxa = 0.f; wxb = (x0 == 63) ? (1.f - tx) : 0.f; }
            else              { xb = x0; wxa = 1.f - tx; wxb = tx; }
            if (y0 < 0)       { yb = 0;  wya = (y0 == -1) ? ty : 0.f; wyb = 0.f; }
            else if (y0 > 62) { yb = 62; wya = 0.f; wyb = (y0 == 63) ? (1.f - ty) : 0.f; }
            else              { yb = y0; wya = 1.f - ty; wyb = ty; }
            float4 cw;
            cw.x = m * wxa * wya; cw.y = m * wxb * wya;
            cw.z = m * wxa * wyb; cw.w = m * wxb * wyb;
            cwr[k] = cw;
            baser[k] = (n << 20) + (yb * 64 + xb) * 256;
        }
    }
    __syncthreads();   // all offs/mask reads done before overwriting CW
#pragma unroll
    for (int k = 0; k < 5; ++k) {
        if (k < 4 || u < 16) {
            int ei = u + 32 * k;
            *(float4*)&CW[q][ei * 4] = cwr[k];
            BASE[q][ei] = baser[k];
        }
    }
    __syncthreads();

    // phase 4: sampling
    int g = u >> 1;
    int c0 = g * 16 + (u & 1) * 8;
    const bf16* xpc = xp + c0;
    f32x2 acc[4];
    acc[0] = (f32x2){0.f, 0.f}; acc[1] = (f32x2){0.f, 0.f};
    acc[2] = (f32x2){0.f, 0.f}; acc[3] = (f32x2){0.f, 0.f};
#pragma unroll
    for (int p = 0; p < 9; ++p) {
        int ei = g * 9 + p;
        float4 cw = *(const float4*)&CW[q][ei * 4];
        int base = BASE[q][ei];
        const bf16* p0 = xpc + base;
        const bf16* p1 = p0 + 16384;          // +1 row (64*256)
        bf16x8 v00 = *(const bf16x8*)(p0);
        bf16x8 v01 = *(const bf16x8*)(p0 + 256);
        bf16x8 v10 = *(const bf16x8*)(p1);
        bf16x8 v11 = *(const bf16x8*)(p1 + 256);
        mac8(acc, v00, cw.x);
        mac8(acc, v01, cw.y);
        mac8(acc, v10, cw.z);
        mac8(acc, v11, cw.w);
    }
    bf16x8 oh;
    oh[0] = (bf16)acc[0].x; oh[1] = (bf16)acc[0].y;
    oh[2] = (bf16)acc[1].x; oh[3] = (bf16)acc[1].y;
    oh[4] = (bf16)acc[2].x; oh[5] = (bf16)acc[2].y;
    oh[6] = (bf16)acc[3].x; oh[7] = (bf16)acc[3].y;
    *(bf16x8*)(rows + (size_t)l * CC + c0) = oh;
}

// ======================= round-3 minimal fallback =========================
__device__ __forceinline__ float dot256f(const float* a, const float* wrow) {
    const float4* w4 = (const float4*)wrow;
    float s = 0.f;
#pragma unroll 16
    for (int i = 0; i < 64; ++i) {
        float4 u = w4[i];
        const float* ap = a + i * 4;
        s += ap[0] * u.x + ap[1] * u.y + ap[2] * u.z + ap[3] * u.w;
    }
    return s;
}

__global__ __launch_bounds__(256) void k_inproj_fb(
    const float* __restrict__ x, const float* __restrict__ in_w,
    const float* __restrict__ in_b, float* __restrict__ xp) {
    int l = blockIdx.x;
    int t = threadIdx.x;
    __shared__ float xa[256];
    xa[t] = x[l * CC + t];
    __syncthreads();
    xp[l * CC + t] = dot256f(xa, in_w + t * CC) + in_b[t];
}

__device__ __forceinline__ float fetch_px_fb(const float* base, int yy, int xx) {
    if (xx < 0 || xx >= 64 || yy < 0 || yy >= 64) return 0.f;
    return base[(yy * 64 + xx) * CC];
}

__global__ __launch_bounds__(256) void k_main_fb(
    const float* __restrict__ x, const float* __restrict__ xp,
    const float* __restrict__ dw_w, const float* __restrict__ dw_b,
    const float* __restrict__ ln_g, const float* __restrict__ ln_b,
    const float* __restrict__ off_w, const float* __restrict__ off_b,
    const float* __restrict__ mask_w, const float* __restrict__ mask_b,
    const float* __restrict__ out_w, const float* __restrict__ out_b,
    float* __restrict__ out) {
    int l = blockIdx.x;
    int t = threadIdx.x;
    int w = l & 63, h = (l >> 6) & 63, n = l >> 12;
    __shared__ float x1[256];
    __shared__ float red[256];
    __shared__ float offs[288];
    __shared__ float ms[144];
    __shared__ float row[256];

    float acc = dw_b[t];
#pragma unroll
    for (int kh = 0; kh < 3; ++kh) {
        int hh = h + kh - 1;
        if (hh < 0 || hh >= 64) continue;
#pragma unroll
        for (int kw = 0; kw < 3; ++kw) {
            int ww = w + kw - 1;
            if (ww < 0 || ww >= 64) continue;
            acc += x[(((n * 64 + hh) * 64) + ww) * CC + t] * dw_w[t * 9 + kh * 3 + kw];
        }
    }
    red[t] = acc;
    __syncthreads();
    for (int s = 128; s > 0; s >>= 1) {
        if (t < s) red[t] += red[t + s];
        __syncthreads();
    }
    float mean = red[0] * (1.0f / 256.0f);
    __syncthreads();
    float d = acc - mean;
    red[t] = d * d;
    __syncthreads();
    for (int s = 128; s > 0; s >>= 1) {
        if (t < s) red[t] += red[t + s];
        __syncthreads();
    }
    float var = red[0] * (1.0f / 256.0f);
    float xn = d * rsqrtf(var + 1e-6f) * ln_g[t] + ln_b[t];
    x1[t] = 0.5f * xn * (1.0f + erff(xn * 0.70710678118654752f));
    __syncthreads();

    offs[t] = dot256f(x1, off_w + t * CC) + off_b[t];
    if (t < 32) {
        int j = 256 + t;
        offs[j] = dot256f(x1, off_w + j * CC) + off_b[j];
    }
    if (t < 144) ms[t] = dot256f(x1, mask_w + t * CC) + mask_b[t];
    __syncthreads();

    if (t < 16) {
        int g = t;
        float mx = -1e30f;
#pragma unroll
        for (int p = 0; p < 9; ++p) mx = fmaxf(mx, ms[g * 9 + p]);
        float s = 0.f, e[9];
#pragma unroll
        for (int p = 0; p < 9; ++p) { e[p] = expf(ms[g * 9 + p] - mx); s += e[p]; }
        float inv = 1.0f / s;
#pragma unroll
        for (int p = 0; p < 9; ++p) ms[g * 9 + p] = e[p] * inv;
    }
    __syncthreads();

    int g = t >> 4;
    const float* base = xp + (size_t)n * 64 * 64 * CC + t;
    float acc2 = 0.f;
#pragma unroll
    for (int p = 0; p < 9; ++p) {
        float ox = offs[g * 18 + p * 2 + 0];
        float oy = offs[g * 18 + p * 2 + 1];
        float ax = (float)(w + (p / 3) - 1) + ox;
        float ay = (float)(h + (p % 3) - 1) + oy;
        float x0f = floorf(ax), y0f = floorf(ay);
        int x0 = (int)x0f, y0 = (int)y0f;
        float tx = ax - x0f, ty = ay - y0f;
        float v00 = fetch_px_fb(base, y0, x0);
        float v01 = fetch_px_fb(base, y0, x0 + 1);
        float v10 = fetch_px_fb(base, y0 + 1, x0);
        float v11 = fetch_px_fb(base, y0 + 1, x0 + 1);
        float bl = (v00 * (1.f - tx) + v01 * tx) * (1.f - ty) +
                   (v10 * (1.f - tx) + v11 * tx) * ty;
        acc2 += ms[g * 9 + p] * bl;
    }
    row[t] = acc2;
    __syncthreads();
    out[l * CC + t] = dot256f(row, out_w + t * CC) + out_b[t];
}

// ==========================================================================
extern "C" void kernel_launch(void* const* d_in, const int* in_sizes, int n_in,
                              void* d_out, int out_size, void* d_ws,
                              size_t ws_size, hipStream_t stream) {
    const float* x      = (const float*)d_in[0];
    const float* dw_w   = (const float*)d_in[1];
    const float* dw_b   = (const float*)d_in[2];
    const float* ln_g   = (const float*)d_in[3];
    const float* ln_b   = (const float*)d_in[4];
    const float* off_w  = (const float*)d_in[5];
    const float* off_b  = (const float*)d_in[6];
    const float* mask_w = (const float*)d_in[7];
    const float* mask_b = (const float*)d_in[8];
    const float* in_w   = (const float*)d_in[9];
    const float* in_b   = (const float*)d_in[10];
    const float* out_w  = (const float*)d_in[11];
    const float* out_b  = (const float*)d_in[12];
    float* out = (float*)d_out;

    const size_t szBF    = (size_t)LL * CC * 2;     // 16,777,216
    const size_t szHEADB = (size_t)LL * HSTR * 2;   // 29,360,128 (padded)
    const size_t szWB    = 1048576;                 // weight blob
    const size_t need    = 3 * szBF + szHEADB + szWB;  // ~81 MB

    dim3 blk(256);
    if (ws_size >= need) {
        char* p = (char*)d_ws;
        bf16* x1h = (bf16*)p; p += szBF;       // reused as rows after head GEMM
        bf16* xpb = (bf16*)p; p += szBF;
        bf16* xb  = (bf16*)p; p += szBF;
        bf16* headb = (bf16*)p; p += szHEADB;
        bf16* in_h  = (bf16*)p; p += 131072;
        bf16* hw_h  = (bf16*)p; p += 262144;   // 512 x 256 bf16 (rows 432+ zeroed)
        bf16* out_h = (bf16*)p; p += 131072;
        float* hbias = (float*)p;
        bf16* rows = x1h;

        k_dwp<<<dim3(8450), blk, 0, stream>>>(
            x, dw_w, dw_b, ln_g, ln_b, x1h, xb,
            in_w, off_w, mask_w, out_w, off_b, mask_b,
            in_h, hw_h, out_h, hbias);
        k_gemm_ih<<<dim3(256, 6), blk, 0, stream>>>(
            xb, x1h, in_h, hw_h, in_b, hbias, xpb, headb);
        k_gather<<<dim3(LL / 8), blk, 0, stream>>>(xpb, headb, rows);
        k_gemm_out<<<dim3(512, 2), blk, 0, stream>>>(rows, out_h, out_b, out);
    } else {
        float* xp = (float*)d_ws;   // 33.5 MB
        k_inproj_fb<<<dim3(LL), blk, 0, stream>>>(x, in_w, in_b, xp);
        k_main_fb<<<dim3(LL), blk, 0, stream>>>(x, xp, dw_w, dw_b, ln_g, ln_b,
                                                off_w, off_b, mask_w, mask_b,
                                                out_w, out_b, out);
    }
}